// Round 4
// baseline (356.809 us; speedup 1.0000x reference)
//
#include <hip/hip_runtime.h>
#include <hip/hip_bf16.h>

typedef unsigned short u16;
typedef __attribute__((ext_vector_type(8))) short s8v;
typedef __attribute__((ext_vector_type(4))) short s4v;
typedef __attribute__((ext_vector_type(4))) float f4v;

__device__ __forceinline__ float s2f(u16 s) {
    unsigned int u = ((unsigned int)s) << 16;
    return __builtin_bit_cast(float, u);
}
__device__ __forceinline__ u16 f2s(float f) {
    __hip_bfloat16 h = __float2bfloat16(f);
    return __builtin_bit_cast(u16, h);
}

// async global->LDS DMA, 16 B per lane; LDS dst must be lane-linear
__device__ __forceinline__ void gl2lds16(const u16* g, u16* l) {
    __builtin_amdgcn_global_load_lds((const __attribute__((address_space(1))) void*)g,
                                     (__attribute__((address_space(3))) void*)l, 16, 0, 0);
}

#define BSZ 4
#define DM 1024
#define QLEN 512
#define MLEN 512
#define KLEN 1024
#define DI 4096
#define NH 16
#define DH 64
#define WIN 256   // valid keys: j = i+257 .. i+512 (exactly 256 per query, never clipped)

// ---- merged f32 -> bf16 weight conversion (5 tensors, 1 launch) ----
__global__ __launch_bounds__(256) void conv_w5(
    const float* __restrict__ s0, const float* __restrict__ s1,
    const float* __restrict__ s2, const float* __restrict__ s3,
    const float* __restrict__ s4,
    u16* __restrict__ d0, u16* __restrict__ d1, u16* __restrict__ d2,
    u16* __restrict__ d3, u16* __restrict__ d4)
{
    const int e0 = 786432, e1 = e0 + 262144, e2 = e1 + 262144,
              e3 = e2 + 1048576, e4 = e3 + 1048576;
    int i = blockIdx.x * 256 + threadIdx.x;
    const float* s; u16* d; int off;
    if (i < e0)      { s = s0; d = d0; off = i; }
    else if (i < e1) { s = s1; d = d1; off = i - e0; }
    else if (i < e2) { s = s2; d = d2; off = i - e1; }
    else if (i < e3) { s = s3; d = d3; off = i - e2; }
    else if (i < e4) { s = s4; d = d4; off = i - e3; }
    else return;
    f4v v = *(const f4v*)&s[(size_t)off * 4];
    s4v o;
#pragma unroll
    for (int k = 0; k < 4; ++k) o[k] = (short)f2s(v[k]);
    *(s4v*)&d[(size_t)off * 4] = o;
}

// ---- transpose f32 (feature-major) -> bf16 (position-major) ----
__global__ __launch_bounds__(256) void trans_f2b(
    const float* __restrict__ src, long sS, int ldS, int colOff,
    u16* __restrict__ dst, long sD, int ldD, int rowOff)
{
    __shared__ float tile[32][33];
    int b = blockIdx.z;
    int t0 = blockIdx.x * 32, f0 = blockIdx.y * 32;
    int tx = threadIdx.x, ty = threadIdx.y;   // (32, 8)
#pragma unroll
    for (int p = 0; p < 4; ++p)
        tile[ty + 8 * p][tx] = src[(size_t)b * sS + (size_t)(f0 + ty + 8 * p) * ldS + colOff + t0 + tx];
    __syncthreads();
#pragma unroll
    for (int p = 0; p < 4; ++p)
        dst[(size_t)b * sD + (size_t)(rowOff + t0 + ty + 8 * p) * ldD + f0 + tx] = f2s(tile[tx][ty + 8 * p]);
}

// ---- transpose-add: dst(bf16, [b][1024][3072]) += src(f32, [b][3072][1024])^T ----
// (covers only the Q,K thirds: f0 < 2048; V third is handled in the gemm epilogue)
__global__ __launch_bounds__(256) void trans_add(
    const float* __restrict__ src, u16* __restrict__ dst)
{
    __shared__ float tile[32][33];
    int b = blockIdx.z;
    int t0 = blockIdx.x * 32, f0 = blockIdx.y * 32;
    int tx = threadIdx.x, ty = threadIdx.y;   // (32, 8)
    const float* S = src + (size_t)b * 3072 * 1024;
    u16* D = dst + (size_t)b * 1024 * 3072;
#pragma unroll
    for (int p = 0; p < 4; ++p)
        tile[ty + 8 * p][tx] = S[(size_t)(f0 + ty + 8 * p) * 1024 + t0 + tx];
    __syncthreads();
#pragma unroll
    for (int p = 0; p < 4; ++p) {
        size_t o = (size_t)(t0 + ty + 8 * p) * 3072 + f0 + tx;
        D[o] = f2s(s2f(D[o]) + tile[tx][ty + 8 * p]);
    }
}

// ---- transpose bf16 (position-major) -> f32 (feature-major) ----
__global__ __launch_bounds__(256) void trans_b2f(
    const u16* __restrict__ src, long sS, int ldS,
    float* __restrict__ dst, long sD, int ldD)
{
    __shared__ float tile[32][33];
    int b = blockIdx.z;
    int t0 = blockIdx.x * 32, f0 = blockIdx.y * 32;
    int tx = threadIdx.x, ty = threadIdx.y;
#pragma unroll
    for (int p = 0; p < 4; ++p)
        tile[ty + 8 * p][tx] = s2f(src[(size_t)b * sS + (size_t)(f0 + ty + 8 * p) * ldS + t0 + tx]);
    __syncthreads();
#pragma unroll
    for (int p = 0; p < 4; ++p)
        dst[(size_t)b * sD + (size_t)(t0 + ty + 8 * p) * ldD + f0 + tx] = tile[tx][ty + 8 * p];
}

// ---- MFMA GEMM (m97-style): C^T(N x M) = A(M x K, bf16) @ B^T(N x K, bf16) ----
// SPLIT>1: each z writes a PRIVATE f32 partial buffer at fOut + z*pstride (no atomics).
// vTout: for m0 >= 2048 (qkv V-third), write transposed to vTout[m-2048][n] with uss
//        V-third added (ussV is feature-major like vT -> coalesced loads).
template<int BN, int SPLIT>
__global__ __launch_bounds__(256) void gemm_bt(
    const u16* __restrict__ A,
    const u16* __restrict__ B,
    u16* __restrict__ C,
    float* __restrict__ fOut,
    int M, int K,
    const float* __restrict__ bias,
    int relu,
    long pstride,
    const float* __restrict__ ussV,
    u16* __restrict__ vTout)
{
    constexpr int BM = 128, BK = 64;
    constexpr int MI = (BN == 128) ? 4 : 2;
    constexpr int NI = 4;
    const int n0 = blockIdx.x * BN, m0 = blockIdx.y * BM;
    const int Ks = K / SPLIT;
    const int kbeg = blockIdx.z * Ks;
    __shared__ __align__(16) u16 As[BM * BK];
    __shared__ __align__(16) u16 Bs[BN * BK];
    const int tid = threadIdx.x, lane = tid & 63, wv = tid >> 6;
    const int l15 = lane & 15, quad = lane >> 4;
    const int wm = (BN == 128) ? (wv >> 1) * 64 : wv * 32;
    const int wn = (BN == 128) ? (wv & 1) * 64 : 0;
    f4v acc[MI][NI] = {};
    for (int kk = kbeg; kk < kbeg + Ks; kk += BK) {
        __syncthreads();
#pragma unroll
        for (int p = 0; p < (BM * 8) / 256; ++p) {
            int c = p * 256 + tid, r = c >> 3, q = c & 7, qs = q ^ (r & 7);
            gl2lds16(&A[(size_t)(m0 + r) * K + kk + qs * 8], &As[c * 8]);
        }
#pragma unroll
        for (int p = 0; p < (BN * 8) / 256; ++p) {
            int c = p * 256 + tid, r = c >> 3, q = c & 7, qs = q ^ (r & 7);
            gl2lds16(&B[(size_t)(n0 + r) * K + kk + qs * 8], &Bs[c * 8]);
        }
        __syncthreads();
#pragma unroll
        for (int k0 = 0; k0 < BK; k0 += 32) {
            s8v af[MI], bf[NI];
#pragma unroll
            for (int mi = 0; mi < MI; ++mi) {
                int r = wm + mi * 16 + l15;
                af[mi] = *(const s8v*)&As[r * BK + ((((k0 >> 3) + quad) ^ (r & 7)) << 3)];
            }
#pragma unroll
            for (int ni = 0; ni < NI; ++ni) {
                int r = wn + ni * 16 + l15;
                bf[ni] = *(const s8v*)&Bs[r * BK + ((((k0 >> 3) + quad) ^ (r & 7)) << 3)];
            }
#pragma unroll
            for (int mi = 0; mi < MI; ++mi)
#pragma unroll
                for (int ni = 0; ni < NI; ++ni)
                    acc[mi][ni] = __builtin_amdgcn_mfma_f32_16x16x32_bf16(af[mi], bf[ni], acc[mi][ni], 0, 0, 0);
        }
    }
    if (SPLIT > 1) {
        float* base = fOut + (long)blockIdx.z * pstride;
#pragma unroll
        for (int mi = 0; mi < MI; ++mi) {
            int m = m0 + wm + mi * 16 + quad * 4;
#pragma unroll
            for (int ni = 0; ni < NI; ++ni) {
                int n = n0 + wn + ni * 16 + l15;
                *(f4v*)&base[(size_t)n * M + m] = acc[mi][ni];   // plain 16B store, no RMW
            }
        }
    } else if (vTout && m0 >= 2048) {
        // V third of qkv: write V^T[d][n] (+ uss V-third, coalesced in this layout)
#pragma unroll
        for (int mi = 0; mi < MI; ++mi) {
            int m = m0 + wm + mi * 16 + quad * 4;
#pragma unroll
            for (int ni = 0; ni < NI; ++ni) {
                int n = n0 + wn + ni * 16 + l15;
                int b = n >> 10, t = n & 1023;
#pragma unroll
                for (int r2 = 0; r2 < 4; ++r2) {
                    float o = acc[mi][ni][r2] + ussV[((size_t)b * 3072 + (m + r2)) * 1024 + t];
                    vTout[(size_t)(m + r2 - 2048) * 4096 + n] = f2s(o);
                }
            }
        }
    } else {
#pragma unroll
        for (int mi = 0; mi < MI; ++mi) {
            int m = m0 + wm + mi * 16 + quad * 4;
            float bv[4] = {0.f, 0.f, 0.f, 0.f};
            if (bias) {
#pragma unroll
                for (int r2 = 0; r2 < 4; ++r2) bv[r2] = bias[m + r2];
            }
#pragma unroll
            for (int ni = 0; ni < NI; ++ni) {
                int n = n0 + wn + ni * 16 + l15;
                float o[4];
#pragma unroll
                for (int r2 = 0; r2 < 4; ++r2) o[r2] = acc[mi][ni][r2] + bv[r2];
                if (relu) {
#pragma unroll
                    for (int r2 = 0; r2 < 4; ++r2) o[r2] = fmaxf(o[r2], 0.f);
                }
                s4v st;
#pragma unroll
                for (int r2 = 0; r2 < 4; ++r2) st[r2] = (short)f2s(o[r2]);
                *(s4v*)&C[(size_t)n * M + m] = st;
            }
        }
    }
}

// ---- MFMA banded flash attention (v2: direct-global K/V, LDS = S only) ----
// Band is EXACTLY 256 keys/query: j = i + 257 .. i + 512 (never clipped by klen).
// Shifted S: S[qi][t], t = j - (j0 + qi), t in [0,256). No masking, no -1e30 init.
// K fragments read direct global (one 128B line per row, fully consumed; zero reuse).
// V fragments read direct global from vT (feature-major V^T produced by qkv gemm).
// P aliased in-place over S rows (u16), padded to 288 k-cols with exact zeros -> 9 clean chunks.
#define QT 16
#define SROW 260   // f32 row stride: 260 % 32 == 4 -> 2-way banks on row-indexed reads
__global__ __launch_bounds__(256, 4) void attn_mfma(
    const u16* __restrict__ WHT,      // (BSZ, KLEN, 3*DM) bf16 (Q,K thirds valid)
    const u16* __restrict__ VT,       // (DM, BSZ*KLEN) bf16 = V^T (+uss), cols n=b*1024+t
    const u16* __restrict__ RT,       // (WIN, DM) bf16
    const float* __restrict__ rwb, const float* __restrict__ rrb,
    u16* __restrict__ avT)            // (BSZ, QLEN, DM) bf16
{
    __shared__ __align__(16) float sS[QT * SROW];   // 16640 B total LDS

    const int qt = blockIdx.x, n = blockIdx.y, b = blockIdx.z;
    const int i0 = qt * QT, j0 = i0 + WIN + 1;
    const int tid = threadIdx.x, lane = tid & 63, wv = tid >> 6;
    const int l15 = lane & 15, quad = lane >> 4;
    const u16* W = WHT + (size_t)b * KLEN * (3 * DM);

    // Q fragments (A-operand rows = l15 = qi), biases baked in
    s8v qac[2], qbd[2];
    {
        int qrow = MLEN + i0 + l15;
#pragma unroll
        for (int kc = 0; kc < 2; ++kc) {
            int col = n * DH + kc * 32 + quad * 8;
            s8v qv = *(const s8v*)&W[(size_t)qrow * (3 * DM) + col];
            s8v a, c;
#pragma unroll
            for (int e = 0; e < 8; ++e) {
                float qf = s2f((u16)qv[e]);
                a[e] = (short)f2s(qf + rwb[col + e]);
                c[e] = (short)f2s(qf + rrb[col + e]);
            }
            qac[kc] = a; qbd[kc] = c;
        }
    }

    // Phase 1: S[qi][t] = AC (QK^T), K direct from global, shifted predicated store
    for (int ci = wv; ci < 17; ci += 4) {
        f4v acc = {};
        const u16* Kr = &W[(size_t)(j0 + ci * 16 + l15) * (3 * DM) + DM + n * DH + quad * 8];
        acc = __builtin_amdgcn_mfma_f32_16x16x32_bf16(qac[0], *(const s8v*)Kr, acc, 0, 0, 0);
        acc = __builtin_amdgcn_mfma_f32_16x16x32_bf16(qac[1], *(const s8v*)(Kr + 32), acc, 0, 0, 0);
#pragma unroll
        for (int r2 = 0; r2 < 4; ++r2) {
            int qi = quad * 4 + r2;
            int t = ci * 16 + l15 - qi;
            if ((unsigned)t < 256u) sS[qi * SROW + t] = acc[r2];
        }
    }
    __syncthreads();

    // Phase 2: S[qi][t'] += BD (rr_q @ R^T), R direct from global, unshifted in t'
#pragma unroll
    for (int cc = 0; cc < 4; ++cc) {
        int ci = wv + cc * 4;
        f4v acc = {};
        const u16* Rr = &RT[(size_t)(ci * 16 + l15) * DM + n * DH + quad * 8];
        acc = __builtin_amdgcn_mfma_f32_16x16x32_bf16(qbd[0], *(const s8v*)Rr, acc, 0, 0, 0);
        acc = __builtin_amdgcn_mfma_f32_16x16x32_bf16(qbd[1], *(const s8v*)(Rr + 32), acc, 0, 0, 0);
#pragma unroll
        for (int r2 = 0; r2 < 4; ++r2) {
            int qi = quad * 4 + r2;
            sS[qi * SROW + ci * 16 + l15] += acc[r2];
        }
    }
    __syncthreads();

    // Phase 3: softmax row g over t in [0,256); write P (bf16) in-place over S row g at
    // c' = qi + 1 + t (so P k-index c' matches V col (j0-1)+c'); zero-pad c' in [0,qi] and
    // [qi+257, 288). 16-lane groups are wave-lockstep: all reads complete before writes.
    {
        int g = tid >> 4, l = tid & 15;
        float vals[16], mx = -1e30f;
#pragma unroll
        for (int k = 0; k < 16; ++k) {
            float s = sS[g * SROW + l + 16 * k] * 0.125f;
            vals[k] = s; mx = fmaxf(mx, s);
        }
        asm volatile("" ::: "memory");   // fence: S f32 reads before u16 P writes (aliased)
#pragma unroll
        for (int d = 1; d < 16; d <<= 1) mx = fmaxf(mx, __shfl_xor(mx, d, 16));
        float sum = 0.f;
#pragma unroll
        for (int k = 0; k < 16; ++k) { vals[k] = __expf(vals[k] - mx); sum += vals[k]; }
#pragma unroll
        for (int d = 1; d < 16; d <<= 1) sum += __shfl_xor(sum, d, 16);
        float inv = 1.f / sum;
        u16* sPr = (u16*)&sS[g * SROW];
#pragma unroll
        for (int k = 0; k < 16; ++k) sPr[g + 1 + l + 16 * k] = f2s(vals[k] * inv);
        sPr[l <= g ? l : 256 + l] = 0;   // zeros [0,g] and [g+257,272)
        sPr[272 + l] = 0;                // zeros [272,288)
    }
    __syncthreads();

    // Phase 4: O = P @ V, V^T fragments direct from global; 9 clean k-chunks of 32
    const u16* sPu = (const u16*)sS;
    const size_t vbase = (size_t)(n * DH + wv * 16 + l15) * 4096
                       + (size_t)b * KLEN + (j0 - 1) + quad * 8;
    f4v o = {};
#pragma unroll
    for (int kc = 0; kc < 9; ++kc) {
        size_t vi = vbase + kc * 32;
        if (vi > (size_t)4194304 - 8) vi = (size_t)4194304 - 8;  // clamp (P=0 there)
        s8v a  = *(const s8v*)&sPu[(size_t)l15 * (2 * SROW) + kc * 32 + quad * 8];
        s8v bb = *(const s8v*)&VT[vi];
        o = __builtin_amdgcn_mfma_f32_16x16x32_bf16(a, bb, o, 0, 0, 0);
    }
#pragma unroll
    for (int r2 = 0; r2 < 4; ++r2) {
        int qi = quad * 4 + r2;
        avT[((size_t)b * QLEN + i0 + qi) * DM + n * DH + wv * 16 + l15] = f2s(o[r2]);
    }
}

// ---- layernorm: out = LN(sum of nparts partials + bias + res_bf16), row-contiguous ----
__global__ __launch_bounds__(256) void ln_f(
    const float* __restrict__ P, long pstride, int nparts,
    const float* __restrict__ bias,
    const u16* __restrict__ res, int resMode, u16* __restrict__ out)
{
    int n = blockIdx.x, tid = threadIdx.x;
    int lane = tid & 63, wv = tid >> 6;
    int f = tid * 4;
    int rrow = resMode ? (((n >> 9) * 2 + 1) * 512 + (n & 511)) : n;
    f4v pv = *(const f4v*)&P[(size_t)n * DM + f];
    for (int p = 1; p < nparts; ++p) {
        const float* Pp = P + (long)p * pstride;
        pv += *(const f4v*)&Pp[(size_t)n * DM + f];
    }
    s4v rv = *(const s4v*)&res[(size_t)rrow * DM + f];
    f4v bv = *(const f4v*)&bias[f];
    float v[4];
#pragma unroll
    for (int k = 0; k < 4; ++k) v[k] = pv[k] + bv[k] + s2f((u16)rv[k]);
    float s = v[0] + v[1] + v[2] + v[3];
    float ss = v[0] * v[0] + v[1] * v[1] + v[2] * v[2] + v[3] * v[3];
#pragma unroll
    for (int d = 1; d < 64; d <<= 1) {
        s += __shfl_xor(s, d, 64);
        ss += __shfl_xor(ss, d, 64);
    }
    __shared__ float ps[4], pss[4];
    if (lane == 0) { ps[wv] = s; pss[wv] = ss; }
    __syncthreads();
    float S = ps[0] + ps[1] + ps[2] + ps[3];
    float SS = pss[0] + pss[1] + pss[2] + pss[3];
    float m = S * (1.f / DM);
    float var = SS * (1.f / DM) - m * m;
    float inv = rsqrtf(fmaxf(var, 0.f) + 1e-5f);
    s4v st;
#pragma unroll
    for (int k = 0; k < 4; ++k) st[k] = (short)f2s((v[k] - m) * inv);
    *(s4v*)&out[(size_t)n * DM + f] = st;
}

extern "C" void kernel_launch(void* const* d_in, const int* in_sizes, int n_in,
                              void* d_out, int out_size, void* d_ws, size_t ws_size,
                              hipStream_t stream) {
    const float* z1ss  = (const float*)d_in[0];
    const float* uss   = (const float*)d_in[1];
    const float* z0    = (const float*)d_in[2];
    const float* pos   = (const float*)d_in[3];
    const float* qkv_w = (const float*)d_in[4];
    const float* r_w   = (const float*)d_in[5];
    const float* rwb   = (const float*)d_in[6];
    const float* rrb   = (const float*)d_in[7];
    const float* o_w   = (const float*)d_in[8];
    const float* o_b   = (const float*)d_in[9];
    const float* ff1_w = (const float*)d_in[10];
    const float* ff1_b = (const float*)d_in[11];
    const float* ff2_w = (const float*)d_in[12];
    const float* ff2_b = (const float*)d_in[13];

    u16* ws = (u16*)d_ws;
    u16* wQ   = ws;             // 3072x1024
    u16* wR   = ws + 3145728;
    u16* wO   = ws + 4194304;
    u16* wF1  = ws + 5242880;
    u16* wF2  = ws + 9437184;
    u16* catT = ws + 13631488;  // (4,1024,1024); later aliased as outT
    u16* whT  = ws + 17825792;  // (4,1024,3072); later aliased as hT
    u16* posT = ws + 30408704;  // (256,1024)
    u16* rT   = ws + 30670848;  // (256,1024)
    u16* avT  = ws + 30932992;  // (2048,1024)
    u16* xT   = ws + 33030144;  // (2048,1024)
    float* pref = (float*)(ws + 35127296);  // 2048x1024 f32  (split partial 0)
    u16* hT   = whT;
    u16* outT = catT;

    // vT (1024 x 4096 bf16, = 8 MB) aliases pref: live only between qkv gemm and attn;
    // pref is first written by o-proj (after attn). OOB tail reads are clamped in-kernel.
    u16* vT = (u16*)pref;

    // split partial 1: workspace offset 0 (wQ+wR region, dead once o-proj/ff2 run)
    float* part1 = (float*)d_ws;
    long pstr = part1 - pref;   // negative f32-element stride between partials

    dim3 tblk(32, 8);

    conv_w5<<<13312, 256, 0, stream>>>(qkv_w, r_w, o_w, ff1_w, ff2_w,
                                       wQ, wR, wO, wF1, wF2);

    trans_f2b<<<dim3(16, 32, BSZ), tblk, 0, stream>>>(z0, (long)DM * MLEN, MLEN, 0,
                                                      catT, (long)KLEN * DM, DM, 0);
    trans_f2b<<<dim3(16, 32, BSZ), tblk, 0, stream>>>(z1ss, (long)DM * QLEN, QLEN, 0,
                                                      catT, (long)KLEN * DM, DM, MLEN);
    trans_f2b<<<dim3(8, 32, 1), tblk, 0, stream>>>(pos, 0, KLEN, KLEN - WIN,
                                                   posT, 0, DM, 0);

    // qkv: whT(4096 x 3072) = (qkv_w @ cat)^T for Q,K thirds; V third -> vT[d][n] (+uss V)
    // BN=128: (128+128)-wide staging per 16 MFMAs -> 1.5x better staging-per-FLOP than BN=64
    gemm_bt<128, 1><<<dim3(32, 24, 1), 256, 0, stream>>>(
        wQ, catT, whT, nullptr, 3 * DM, DM, nullptr, 0, 0, uss, vT);

    // whT += uss^T for Q,K thirds only
    trans_add<<<dim3(32, 64, BSZ), tblk, 0, stream>>>(uss, whT);

    // r: rT(256 x 1024) = (r_w @ pos[:,768:])^T
    gemm_bt<64, 1><<<dim3(4, 8, 1), 256, 0, stream>>>(
        wR, posT, rT, nullptr, DM, DM, nullptr, 0, 0, nullptr, nullptr);

    // MFMA banded attention -> avT  (LDS = 16.6 KB, direct-global K/V)
    attn_mfma<<<dim3(QLEN / QT, NH, BSZ), 256, 0, stream>>>(whT, vT, rT, rwb, rrb, avT);

    // o-proj split-2, private partials (overwrites pref/vT: attn already consumed vT)
    gemm_bt<64, 2><<<dim3(32, 8, 2), 256, 0, stream>>>(
        wO, avT, nullptr, pref, DM, DM, nullptr, 0, pstr, nullptr, nullptr);

    ln_f<<<2048, 256, 0, stream>>>(pref, pstr, 2, o_b, catT, 1, xT);

    // ff1  (BN=128)
    gemm_bt<128, 1><<<dim3(16, 32, 1), 256, 0, stream>>>(
        wF1, xT, hT, nullptr, DI, DM, ff1_b, 1, 0, nullptr, nullptr);

    // ff2 split-2, private partials
    gemm_bt<64, 2><<<dim3(32, 8, 2), 256, 0, stream>>>(
        wF2, hT, nullptr, pref, DM, DI, nullptr, 0, pstr, nullptr, nullptr);

    ln_f<<<2048, 256, 0, stream>>>(pref, pstr, 2, ff2_b, xT, 0, outT);

    trans_b2f<<<dim3(32, 16, BSZ), tblk, 0, stream>>>(outT, (long)QLEN * DM, DM,
                                                      (float*)d_out, (long)DM * QLEN, QLEN);
}

// Round 5
// 346.966 us; speedup vs baseline: 1.0284x; 1.0284x over previous
//
#include <hip/hip_runtime.h>
#include <hip/hip_bf16.h>

typedef unsigned short u16;
typedef __attribute__((ext_vector_type(8))) short s8v;
typedef __attribute__((ext_vector_type(4))) short s4v;
typedef __attribute__((ext_vector_type(4))) float f4v;

__device__ __forceinline__ float s2f(u16 s) {
    unsigned int u = ((unsigned int)s) << 16;
    return __builtin_bit_cast(float, u);
}
__device__ __forceinline__ u16 f2s(float f) {
    __hip_bfloat16 h = __float2bfloat16(f);
    return __builtin_bit_cast(u16, h);
}

// async global->LDS DMA, 16 B per lane; LDS dst must be lane-linear
__device__ __forceinline__ void gl2lds16(const u16* g, u16* l) {
    __builtin_amdgcn_global_load_lds((const __attribute__((address_space(1))) void*)g,
                                     (__attribute__((address_space(3))) void*)l, 16, 0, 0);
}

#define BSZ 4
#define DM 1024
#define QLEN 512
#define MLEN 512
#define KLEN 1024
#define DI 4096
#define NH 16
#define DH 64
#define WIN 256   // valid keys: j = i+257 .. i+512 (exactly 256 per query, never clipped)

// ---- merged f32 -> bf16 weight conversion (5 tensors, 1 launch) ----
__global__ __launch_bounds__(256) void conv_w5(
    const float* __restrict__ s0, const float* __restrict__ s1,
    const float* __restrict__ s2, const float* __restrict__ s3,
    const float* __restrict__ s4,
    u16* __restrict__ d0, u16* __restrict__ d1, u16* __restrict__ d2,
    u16* __restrict__ d3, u16* __restrict__ d4)
{
    const int e0 = 786432, e1 = e0 + 262144, e2 = e1 + 262144,
              e3 = e2 + 1048576, e4 = e3 + 1048576;
    int i = blockIdx.x * 256 + threadIdx.x;
    const float* s; u16* d; int off;
    if (i < e0)      { s = s0; d = d0; off = i; }
    else if (i < e1) { s = s1; d = d1; off = i - e0; }
    else if (i < e2) { s = s2; d = d2; off = i - e1; }
    else if (i < e3) { s = s3; d = d3; off = i - e2; }
    else if (i < e4) { s = s4; d = d4; off = i - e3; }
    else return;
    f4v v = *(const f4v*)&s[(size_t)off * 4];
    s4v o;
#pragma unroll
    for (int k = 0; k < 4; ++k) o[k] = (short)f2s(v[k]);
    *(s4v*)&d[(size_t)off * 4] = o;
}

// ---- transpose f32 (feature-major) -> bf16 (position-major) ----
__global__ __launch_bounds__(256) void trans_f2b(
    const float* __restrict__ src, long sS, int ldS, int colOff,
    u16* __restrict__ dst, long sD, int ldD, int rowOff)
{
    __shared__ float tile[32][33];
    int b = blockIdx.z;
    int t0 = blockIdx.x * 32, f0 = blockIdx.y * 32;
    int tx = threadIdx.x, ty = threadIdx.y;   // (32, 8)
#pragma unroll
    for (int p = 0; p < 4; ++p)
        tile[ty + 8 * p][tx] = src[(size_t)b * sS + (size_t)(f0 + ty + 8 * p) * ldS + colOff + t0 + tx];
    __syncthreads();
#pragma unroll
    for (int p = 0; p < 4; ++p)
        dst[(size_t)b * sD + (size_t)(rowOff + t0 + ty + 8 * p) * ldD + f0 + tx] = f2s(tile[tx][ty + 8 * p]);
}

// ---- uss add: Q/K thirds transpose-add into whT; V third straight-add into vT ----
// y < 64 : whT[b][t][f0+..] += uss[b][f0+..][t]^T   (LDS 32x33 transpose)
// y >= 64: vT[d][b*1024+t]  += uss[b][2048+d][t]    (same layout, no transpose)
__global__ __launch_bounds__(256) void uss_add(
    const float* __restrict__ uss, u16* __restrict__ whT, u16* __restrict__ vT)
{
    __shared__ float tile[32][33];
    int b = blockIdx.z;
    int t0 = blockIdx.x * 32, fy = blockIdx.y;
    int tx = threadIdx.x, ty = threadIdx.y;   // (32, 8)
    const float* S = uss + (size_t)b * 3072 * 1024;
    if (fy < 64) {
        int f0 = fy * 32;
        u16* D = whT + (size_t)b * 1024 * 3072;
#pragma unroll
        for (int p = 0; p < 4; ++p)
            tile[ty + 8 * p][tx] = S[(size_t)(f0 + ty + 8 * p) * 1024 + t0 + tx];
        __syncthreads();
#pragma unroll
        for (int p = 0; p < 4; ++p) {
            size_t o = (size_t)(t0 + ty + 8 * p) * 3072 + f0 + tx;
            D[o] = f2s(s2f(D[o]) + tile[tx][ty + 8 * p]);
        }
    } else {
        int d0 = (fy - 64) * 32;
#pragma unroll
        for (int p = 0; p < 4; ++p) {
            int d = d0 + ty + 8 * p;
            size_t ui = ((size_t)2048 + d) * 1024 + t0 + tx;
            size_t vi = (size_t)d * 4096 + (size_t)b * KLEN + t0 + tx;
            vT[vi] = f2s(s2f(vT[vi]) + S[ui]);
        }
    }
}

// ---- transpose bf16 (position-major) -> f32 (feature-major) ----
__global__ __launch_bounds__(256) void trans_b2f(
    const u16* __restrict__ src, long sS, int ldS,
    float* __restrict__ dst, long sD, int ldD)
{
    __shared__ float tile[32][33];
    int b = blockIdx.z;
    int t0 = blockIdx.x * 32, f0 = blockIdx.y * 32;
    int tx = threadIdx.x, ty = threadIdx.y;
#pragma unroll
    for (int p = 0; p < 4; ++p)
        tile[ty + 8 * p][tx] = s2f(src[(size_t)b * sS + (size_t)(f0 + ty + 8 * p) * ldS + t0 + tx]);
    __syncthreads();
#pragma unroll
    for (int p = 0; p < 4; ++p)
        dst[(size_t)b * sD + (size_t)(t0 + ty + 8 * p) * ldD + f0 + tx] = tile[tx][ty + 8 * p];
}

// ---- MFMA GEMM (m97-style): C^T(N x M) = A(M x K, bf16) @ B^T(N x K, bf16) ----
// SPLIT>1: each z writes a PRIVATE f32 partial buffer at fOut + z*pstride (no atomics).
// vTout: for m0 >= 2048 (qkv V-third), write transposed to vTout[m-2048][n]
//        (pure coalesced stores; uss V-third added later by uss_add).
template<int BN, int SPLIT>
__global__ __launch_bounds__(256) void gemm_bt(
    const u16* __restrict__ A,
    const u16* __restrict__ B,
    u16* __restrict__ C,
    float* __restrict__ fOut,
    int M, int K,
    const float* __restrict__ bias,
    int relu,
    long pstride,
    u16* __restrict__ vTout)
{
    constexpr int BM = 128, BK = 64;
    constexpr int MI = (BN == 128) ? 4 : 2;
    constexpr int NI = 4;
    const int n0 = blockIdx.x * BN, m0 = blockIdx.y * BM;
    const int Ks = K / SPLIT;
    const int kbeg = blockIdx.z * Ks;
    __shared__ __align__(16) u16 As[BM * BK];
    __shared__ __align__(16) u16 Bs[BN * BK];
    const int tid = threadIdx.x, lane = tid & 63, wv = tid >> 6;
    const int l15 = lane & 15, quad = lane >> 4;
    const int wm = (BN == 128) ? (wv >> 1) * 64 : wv * 32;
    const int wn = (BN == 128) ? (wv & 1) * 64 : 0;
    f4v acc[MI][NI] = {};
    for (int kk = kbeg; kk < kbeg + Ks; kk += BK) {
        __syncthreads();
#pragma unroll
        for (int p = 0; p < (BM * 8) / 256; ++p) {
            int c = p * 256 + tid, r = c >> 3, q = c & 7, qs = q ^ (r & 7);
            gl2lds16(&A[(size_t)(m0 + r) * K + kk + qs * 8], &As[c * 8]);
        }
#pragma unroll
        for (int p = 0; p < (BN * 8) / 256; ++p) {
            int c = p * 256 + tid, r = c >> 3, q = c & 7, qs = q ^ (r & 7);
            gl2lds16(&B[(size_t)(n0 + r) * K + kk + qs * 8], &Bs[c * 8]);
        }
        __syncthreads();
#pragma unroll
        for (int k0 = 0; k0 < BK; k0 += 32) {
            s8v af[MI], bf[NI];
#pragma unroll
            for (int mi = 0; mi < MI; ++mi) {
                int r = wm + mi * 16 + l15;
                af[mi] = *(const s8v*)&As[r * BK + ((((k0 >> 3) + quad) ^ (r & 7)) << 3)];
            }
#pragma unroll
            for (int ni = 0; ni < NI; ++ni) {
                int r = wn + ni * 16 + l15;
                bf[ni] = *(const s8v*)&Bs[r * BK + ((((k0 >> 3) + quad) ^ (r & 7)) << 3)];
            }
#pragma unroll
            for (int mi = 0; mi < MI; ++mi)
#pragma unroll
                for (int ni = 0; ni < NI; ++ni)
                    acc[mi][ni] = __builtin_amdgcn_mfma_f32_16x16x32_bf16(af[mi], bf[ni], acc[mi][ni], 0, 0, 0);
        }
    }
    if (SPLIT > 1) {
        float* base = fOut + (long)blockIdx.z * pstride;
#pragma unroll
        for (int mi = 0; mi < MI; ++mi) {
            int m = m0 + wm + mi * 16 + quad * 4;
#pragma unroll
            for (int ni = 0; ni < NI; ++ni) {
                int n = n0 + wn + ni * 16 + l15;
                *(f4v*)&base[(size_t)n * M + m] = acc[mi][ni];   // plain 16B store, no RMW
            }
        }
    } else if (vTout && m0 >= 2048) {
        // V third of qkv: pure coalesced stores to V^T[d][n]
#pragma unroll
        for (int mi = 0; mi < MI; ++mi) {
            int m = m0 + wm + mi * 16 + quad * 4;
#pragma unroll
            for (int ni = 0; ni < NI; ++ni) {
                int n = n0 + wn + ni * 16 + l15;
#pragma unroll
                for (int r2 = 0; r2 < 4; ++r2)
                    vTout[(size_t)(m + r2 - 2048) * 4096 + n] = f2s(acc[mi][ni][r2]);
            }
        }
    } else {
#pragma unroll
        for (int mi = 0; mi < MI; ++mi) {
            int m = m0 + wm + mi * 16 + quad * 4;
            float bv[4] = {0.f, 0.f, 0.f, 0.f};
            if (bias) {
#pragma unroll
                for (int r2 = 0; r2 < 4; ++r2) bv[r2] = bias[m + r2];
            }
#pragma unroll
            for (int ni = 0; ni < NI; ++ni) {
                int n = n0 + wn + ni * 16 + l15;
                float o[4];
#pragma unroll
                for (int r2 = 0; r2 < 4; ++r2) o[r2] = acc[mi][ni][r2] + bv[r2];
                if (relu) {
#pragma unroll
                    for (int r2 = 0; r2 < 4; ++r2) o[r2] = fmaxf(o[r2], 0.f);
                }
                s4v st;
#pragma unroll
                for (int r2 = 0; r2 < 4; ++r2) st[r2] = (short)f2s(o[r2]);
                *(s4v*)&C[(size_t)n * M + m] = st;
            }
        }
    }
}

// ---- MFMA banded flash attention (v2: direct-global K/V, LDS = S only) ----
// Band is EXACTLY 256 keys/query: j = i + 257 .. i + 512 (never clipped by klen).
// Shifted S: S[qi][t], t = j - (j0 + qi), t in [0,256). No masking, no -1e30 init.
// K fragments read direct global (one 128B line per row, fully consumed; zero reuse).
// V fragments read direct global from vT (feature-major V^T produced by qkv gemm).
// P aliased in-place over S rows (u16), padded to 288 k-cols with exact zeros -> 9 clean chunks.
#define QT 16
#define SROW 260   // f32 row stride: 260 % 32 == 4 -> 2-way banks on row-indexed reads
__global__ __launch_bounds__(256, 4) void attn_mfma(
    const u16* __restrict__ WHT,      // (BSZ, KLEN, 3*DM) bf16 (Q,K thirds valid)
    const u16* __restrict__ VT,       // (DM, BSZ*KLEN) bf16 = V^T (+uss), cols n=b*1024+t
    const u16* __restrict__ RT,       // (WIN, DM) bf16
    const float* __restrict__ rwb, const float* __restrict__ rrb,
    u16* __restrict__ avT)            // (BSZ, QLEN, DM) bf16
{
    __shared__ __align__(16) float sS[QT * SROW];   // 16640 B total LDS

    const int qt = blockIdx.x, n = blockIdx.y, b = blockIdx.z;
    const int i0 = qt * QT, j0 = i0 + WIN + 1;
    const int tid = threadIdx.x, lane = tid & 63, wv = tid >> 6;
    const int l15 = lane & 15, quad = lane >> 4;
    const u16* W = WHT + (size_t)b * KLEN * (3 * DM);

    // Q fragments (A-operand rows = l15 = qi), biases baked in
    s8v qac[2], qbd[2];
    {
        int qrow = MLEN + i0 + l15;
#pragma unroll
        for (int kc = 0; kc < 2; ++kc) {
            int col = n * DH + kc * 32 + quad * 8;
            s8v qv = *(const s8v*)&W[(size_t)qrow * (3 * DM) + col];
            s8v a, c;
#pragma unroll
            for (int e = 0; e < 8; ++e) {
                float qf = s2f((u16)qv[e]);
                a[e] = (short)f2s(qf + rwb[col + e]);
                c[e] = (short)f2s(qf + rrb[col + e]);
            }
            qac[kc] = a; qbd[kc] = c;
        }
    }

    // Phase 1: S[qi][t] = AC (QK^T), K direct from global, shifted predicated store
    for (int ci = wv; ci < 17; ci += 4) {
        f4v acc = {};
        const u16* Kr = &W[(size_t)(j0 + ci * 16 + l15) * (3 * DM) + DM + n * DH + quad * 8];
        acc = __builtin_amdgcn_mfma_f32_16x16x32_bf16(qac[0], *(const s8v*)Kr, acc, 0, 0, 0);
        acc = __builtin_amdgcn_mfma_f32_16x16x32_bf16(qac[1], *(const s8v*)(Kr + 32), acc, 0, 0, 0);
#pragma unroll
        for (int r2 = 0; r2 < 4; ++r2) {
            int qi = quad * 4 + r2;
            int t = ci * 16 + l15 - qi;
            if ((unsigned)t < 256u) sS[qi * SROW + t] = acc[r2];
        }
    }
    __syncthreads();

    // Phase 2: S[qi][t'] += BD (rr_q @ R^T), R direct from global, unshifted in t'
#pragma unroll
    for (int cc = 0; cc < 4; ++cc) {
        int ci = wv + cc * 4;
        f4v acc = {};
        const u16* Rr = &RT[(size_t)(ci * 16 + l15) * DM + n * DH + quad * 8];
        acc = __builtin_amdgcn_mfma_f32_16x16x32_bf16(qbd[0], *(const s8v*)Rr, acc, 0, 0, 0);
        acc = __builtin_amdgcn_mfma_f32_16x16x32_bf16(qbd[1], *(const s8v*)(Rr + 32), acc, 0, 0, 0);
#pragma unroll
        for (int r2 = 0; r2 < 4; ++r2) {
            int qi = quad * 4 + r2;
            sS[qi * SROW + ci * 16 + l15] += acc[r2];
        }
    }
    __syncthreads();

    // Phase 3: softmax row g over t in [0,256); write P (bf16) in-place over S row g at
    // c' = qi + 1 + t (so P k-index c' matches V col (j0-1)+c'); zero-pad c' in [0,qi] and
    // [qi+257, 288). 16-lane groups are wave-lockstep: all reads complete before writes.
    {
        int g = tid >> 4, l = tid & 15;
        float vals[16], mx = -1e30f;
#pragma unroll
        for (int k = 0; k < 16; ++k) {
            float s = sS[g * SROW + l + 16 * k] * 0.125f;
            vals[k] = s; mx = fmaxf(mx, s);
        }
        asm volatile("" ::: "memory");   // fence: S f32 reads before u16 P writes (aliased)
#pragma unroll
        for (int d = 1; d < 16; d <<= 1) mx = fmaxf(mx, __shfl_xor(mx, d, 16));
        float sum = 0.f;
#pragma unroll
        for (int k = 0; k < 16; ++k) { vals[k] = __expf(vals[k] - mx); sum += vals[k]; }
#pragma unroll
        for (int d = 1; d < 16; d <<= 1) sum += __shfl_xor(sum, d, 16);
        float inv = 1.f / sum;
        u16* sPr = (u16*)&sS[g * SROW];
#pragma unroll
        for (int k = 0; k < 16; ++k) sPr[g + 1 + l + 16 * k] = f2s(vals[k] * inv);
        sPr[l <= g ? l : 256 + l] = 0;   // zeros [0,g] and [g+257,272)
        sPr[272 + l] = 0;                // zeros [272,288)
    }
    __syncthreads();

    // Phase 4: O = P @ V, V^T fragments direct from global; 9 clean k-chunks of 32
    const u16* sPu = (const u16*)sS;
    const size_t vbase = (size_t)(n * DH + wv * 16 + l15) * 4096
                       + (size_t)b * KLEN + (j0 - 1) + quad * 8;
    f4v o = {};
#pragma unroll
    for (int kc = 0; kc < 9; ++kc) {
        size_t vi = vbase + kc * 32;
        if (vi > (size_t)4194304 - 8) vi = (size_t)4194304 - 8;  // clamp (P=0 there)
        s8v a  = *(const s8v*)&sPu[(size_t)l15 * (2 * SROW) + kc * 32 + quad * 8];
        s8v bb = *(const s8v*)&VT[vi];
        o = __builtin_amdgcn_mfma_f32_16x16x32_bf16(a, bb, o, 0, 0, 0);
    }
#pragma unroll
    for (int r2 = 0; r2 < 4; ++r2) {
        int qi = quad * 4 + r2;
        avT[((size_t)b * QLEN + i0 + qi) * DM + n * DH + wv * 16 + l15] = f2s(o[r2]);
    }
}

// ---- layernorm: out = LN(sum of nparts partials + bias + res_bf16), row-contiguous ----
__global__ __launch_bounds__(256) void ln_f(
    const float* __restrict__ P, long pstride, int nparts,
    const float* __restrict__ bias,
    const u16* __restrict__ res, int resMode, u16* __restrict__ out)
{
    int n = blockIdx.x, tid = threadIdx.x;
    int lane = tid & 63, wv = tid >> 6;
    int f = tid * 4;
    int rrow = resMode ? (((n >> 9) * 2 + 1) * 512 + (n & 511)) : n;
    f4v pv = *(const f4v*)&P[(size_t)n * DM + f];
    for (int p = 1; p < nparts; ++p) {
        const float* Pp = P + (long)p * pstride;
        pv += *(const f4v*)&Pp[(size_t)n * DM + f];
    }
    s4v rv = *(const s4v*)&res[(size_t)rrow * DM + f];
    f4v bv = *(const f4v*)&bias[f];
    float v[4];
#pragma unroll
    for (int k = 0; k < 4; ++k) v[k] = pv[k] + bv[k] + s2f((u16)rv[k]);
    float s = v[0] + v[1] + v[2] + v[3];
    float ss = v[0] * v[0] + v[1] * v[1] + v[2] * v[2] + v[3] * v[3];
#pragma unroll
    for (int d = 1; d < 64; d <<= 1) {
        s += __shfl_xor(s, d, 64);
        ss += __shfl_xor(ss, d, 64);
    }
    __shared__ float ps[4], pss[4];
    if (lane == 0) { ps[wv] = s; pss[wv] = ss; }
    __syncthreads();
    float S = ps[0] + ps[1] + ps[2] + ps[3];
    float SS = pss[0] + pss[1] + pss[2] + pss[3];
    float m = S * (1.f / DM);
    float var = SS * (1.f / DM) - m * m;
    float inv = rsqrtf(fmaxf(var, 0.f) + 1e-5f);
    s4v st;
#pragma unroll
    for (int k = 0; k < 4; ++k) st[k] = (short)f2s((v[k] - m) * inv);
    *(s4v*)&out[(size_t)n * DM + f] = st;
}

extern "C" void kernel_launch(void* const* d_in, const int* in_sizes, int n_in,
                              void* d_out, int out_size, void* d_ws, size_t ws_size,
                              hipStream_t stream) {
    const float* z1ss  = (const float*)d_in[0];
    const float* uss   = (const float*)d_in[1];
    const float* z0    = (const float*)d_in[2];
    const float* pos   = (const float*)d_in[3];
    const float* qkv_w = (const float*)d_in[4];
    const float* r_w   = (const float*)d_in[5];
    const float* rwb   = (const float*)d_in[6];
    const float* rrb   = (const float*)d_in[7];
    const float* o_w   = (const float*)d_in[8];
    const float* o_b   = (const float*)d_in[9];
    const float* ff1_w = (const float*)d_in[10];
    const float* ff1_b = (const float*)d_in[11];
    const float* ff2_w = (const float*)d_in[12];
    const float* ff2_b = (const float*)d_in[13];

    u16* ws = (u16*)d_ws;
    u16* wQ   = ws;             // 3072x1024
    u16* wR   = ws + 3145728;
    u16* wO   = ws + 4194304;
    u16* wF1  = ws + 5242880;
    u16* wF2  = ws + 9437184;
    u16* catT = ws + 13631488;  // (4,1024,1024); later aliased as outT
    u16* whT  = ws + 17825792;  // (4,1024,3072); later aliased as hT
    u16* posT = ws + 30408704;  // (256,1024)
    u16* rT   = ws + 30670848;  // (256,1024)
    u16* avT  = ws + 30932992;  // (2048,1024)
    u16* xT   = ws + 33030144;  // (2048,1024)
    float* pref = (float*)(ws + 35127296);  // 2048x1024 f32  (split partial 0)
    u16* hT   = whT;
    u16* outT = catT;

    // vT (1024 x 4096 bf16, = 8 MB) aliases pref: live only between qkv gemm and attn;
    // pref is first written by o-proj (after attn). OOB tail reads are clamped in-kernel.
    u16* vT = (u16*)pref;

    // split partial 1: workspace offset 0 (wQ+wR region, dead once o-proj/ff2 run)
    float* part1 = (float*)d_ws;
    long pstr = part1 - pref;   // negative f32-element stride between partials

    dim3 tblk(32, 8);

    conv_w5<<<13312, 256, 0, stream>>>(qkv_w, r_w, o_w, ff1_w, ff2_w,
                                       wQ, wR, wO, wF1, wF2);

    trans_f2b<<<dim3(16, 32, BSZ), tblk, 0, stream>>>(z0, (long)DM * MLEN, MLEN, 0,
                                                      catT, (long)KLEN * DM, DM, 0);
    trans_f2b<<<dim3(16, 32, BSZ), tblk, 0, stream>>>(z1ss, (long)DM * QLEN, QLEN, 0,
                                                      catT, (long)KLEN * DM, DM, MLEN);
    trans_f2b<<<dim3(8, 32, 1), tblk, 0, stream>>>(pos, 0, KLEN, KLEN - WIN,
                                                   posT, 0, DM, 0);

    // qkv: whT(4096 x 3072) = (qkv_w @ cat)^T for Q,K thirds; V third -> vT[d][n]
    // (BN=64: R3 A/B showed BN=128 regresses; uss fully out of the epilogue now)
    gemm_bt<64, 1><<<dim3(64, 24, 1), 256, 0, stream>>>(
        wQ, catT, whT, nullptr, 3 * DM, DM, nullptr, 0, 0, vT);

    // uss: Q/K thirds transpose-add into whT; V third straight-add into vT
    uss_add<<<dim3(32, 96, BSZ), tblk, 0, stream>>>(uss, whT, vT);

    // r: rT(256 x 1024) = (r_w @ pos[:,768:])^T
    gemm_bt<64, 1><<<dim3(4, 8, 1), 256, 0, stream>>>(
        wR, posT, rT, nullptr, DM, DM, nullptr, 0, 0, nullptr);

    // MFMA banded attention -> avT  (LDS = 16.6 KB, direct-global K/V)
    attn_mfma<<<dim3(QLEN / QT, NH, BSZ), 256, 0, stream>>>(whT, vT, rT, rwb, rrb, avT);

    // o-proj split-2, private partials (overwrites pref/vT: attn already consumed vT)
    gemm_bt<64, 2><<<dim3(32, 8, 2), 256, 0, stream>>>(
        wO, avT, nullptr, pref, DM, DM, nullptr, 0, pstr, nullptr);

    ln_f<<<2048, 256, 0, stream>>>(pref, pstr, 2, o_b, catT, 1, xT);

    // ff1  (BN=64)
    gemm_bt<64, 1><<<dim3(32, 32, 1), 256, 0, stream>>>(
        wF1, xT, hT, nullptr, DI, DM, ff1_b, 1, 0, nullptr);

    // ff2 split-2, private partials
    gemm_bt<64, 2><<<dim3(32, 8, 2), 256, 0, stream>>>(
        wF2, hT, nullptr, pref, DM, DI, nullptr, 0, pstr, nullptr);

    ln_f<<<2048, 256, 0, stream>>>(pref, pstr, 2, ff2_b, xT, 0, outT);

    trans_b2f<<<dim3(32, 16, BSZ), tblk, 0, stream>>>(outT, (long)QLEN * DM, DM,
                                                      (float*)d_out, (long)DM * QLEN, QLEN);
}

// Round 6
// 337.477 us; speedup vs baseline: 1.0573x; 1.0281x over previous
//
#include <hip/hip_runtime.h>
#include <hip/hip_bf16.h>

typedef unsigned short u16;
typedef __attribute__((ext_vector_type(8))) short s8v;
typedef __attribute__((ext_vector_type(4))) short s4v;
typedef __attribute__((ext_vector_type(4))) float f4v;

__device__ __forceinline__ float s2f(u16 s) {
    unsigned int u = ((unsigned int)s) << 16;
    return __builtin_bit_cast(float, u);
}
__device__ __forceinline__ u16 f2s(float f) {
    __hip_bfloat16 h = __float2bfloat16(f);
    return __builtin_bit_cast(u16, h);
}

// async global->LDS DMA, 16 B per lane; LDS dst must be lane-linear
__device__ __forceinline__ void gl2lds16(const u16* g, u16* l) {
    __builtin_amdgcn_global_load_lds((const __attribute__((address_space(1))) void*)g,
                                     (__attribute__((address_space(3))) void*)l, 16, 0, 0);
}

#define BSZ 4
#define DM 1024
#define QLEN 512
#define MLEN 512
#define KLEN 1024
#define DI 4096
#define NH 16
#define DH 64
#define WIN 256   // valid keys: j = i+257 .. i+512 (exactly 256 per query, never clipped)

// ---- merged f32 -> bf16 weight conversion (5 tensors, 1 launch) ----
__global__ __launch_bounds__(256) void conv_w5(
    const float* __restrict__ s0, const float* __restrict__ s1,
    const float* __restrict__ s2, const float* __restrict__ s3,
    const float* __restrict__ s4,
    u16* __restrict__ d0, u16* __restrict__ d1, u16* __restrict__ d2,
    u16* __restrict__ d3, u16* __restrict__ d4)
{
    const int e0 = 786432, e1 = e0 + 262144, e2 = e1 + 262144,
              e3 = e2 + 1048576, e4 = e3 + 1048576;
    int i = blockIdx.x * 256 + threadIdx.x;
    const float* s; u16* d; int off;
    if (i < e0)      { s = s0; d = d0; off = i; }
    else if (i < e1) { s = s1; d = d1; off = i - e0; }
    else if (i < e2) { s = s2; d = d2; off = i - e1; }
    else if (i < e3) { s = s3; d = d3; off = i - e2; }
    else if (i < e4) { s = s4; d = d4; off = i - e3; }
    else return;
    f4v v = *(const f4v*)&s[(size_t)off * 4];
    s4v o;
#pragma unroll
    for (int k = 0; k < 4; ++k) o[k] = (short)f2s(v[k]);
    *(s4v*)&d[(size_t)off * 4] = o;
}

// ---- transpose f32 (feature-major) -> bf16 (position-major) ----
__global__ __launch_bounds__(256) void trans_f2b(
    const float* __restrict__ src, long sS, int ldS, int colOff,
    u16* __restrict__ dst, long sD, int ldD, int rowOff)
{
    __shared__ float tile[32][33];
    int b = blockIdx.z;
    int t0 = blockIdx.x * 32, f0 = blockIdx.y * 32;
    int tx = threadIdx.x, ty = threadIdx.y;   // (32, 8)
#pragma unroll
    for (int p = 0; p < 4; ++p)
        tile[ty + 8 * p][tx] = src[(size_t)b * sS + (size_t)(f0 + ty + 8 * p) * ldS + colOff + t0 + tx];
    __syncthreads();
#pragma unroll
    for (int p = 0; p < 4; ++p)
        dst[(size_t)b * sD + (size_t)(rowOff + t0 + ty + 8 * p) * ldD + f0 + tx] = f2s(tile[tx][ty + 8 * p]);
}

// ---- uss add: Q/K thirds transpose-add into whT; V third straight-add into vT ----
// y < 64 : whT[b][t][f0+..] += uss[b][f0+..][t]^T   (LDS 32x33 transpose)
// y >= 64: vT[d][b*1024+t]  += uss[b][2048+d][t]    (same layout, no transpose)
// Q-third (fy<32) only needed for t >= 512 (w_head_q takes last qlen positions).
__global__ __launch_bounds__(256) void uss_add(
    const float* __restrict__ uss, u16* __restrict__ whT, u16* __restrict__ vT)
{
    __shared__ float tile[32][33];
    int b = blockIdx.z;
    int t0 = blockIdx.x * 32, fy = blockIdx.y;
    int tx = threadIdx.x, ty = threadIdx.y;   // (32, 8)
    if (fy < 32 && t0 < 512) return;          // dead Q-third region
    const float* S = uss + (size_t)b * 3072 * 1024;
    if (fy < 64) {
        int f0 = fy * 32;
        u16* D = whT + (size_t)b * 1024 * 3072;
#pragma unroll
        for (int p = 0; p < 4; ++p)
            tile[ty + 8 * p][tx] = S[(size_t)(f0 + ty + 8 * p) * 1024 + t0 + tx];
        __syncthreads();
#pragma unroll
        for (int p = 0; p < 4; ++p) {
            size_t o = (size_t)(t0 + ty + 8 * p) * 3072 + f0 + tx;
            D[o] = f2s(s2f(D[o]) + tile[tx][ty + 8 * p]);
        }
    } else {
        int d0 = (fy - 64) * 32;
#pragma unroll
        for (int p = 0; p < 4; ++p) {
            int d = d0 + ty + 8 * p;
            size_t ui = ((size_t)2048 + d) * 1024 + t0 + tx;
            size_t vi = (size_t)d * 4096 + (size_t)b * KLEN + t0 + tx;
            vT[vi] = f2s(s2f(vT[vi]) + S[ui]);
        }
    }
}

// ---- transpose bf16 (position-major) -> f32 (feature-major) ----
__global__ __launch_bounds__(256) void trans_b2f(
    const u16* __restrict__ src, long sS, int ldS,
    float* __restrict__ dst, long sD, int ldD)
{
    __shared__ float tile[32][33];
    int b = blockIdx.z;
    int t0 = blockIdx.x * 32, f0 = blockIdx.y * 32;
    int tx = threadIdx.x, ty = threadIdx.y;
#pragma unroll
    for (int p = 0; p < 4; ++p)
        tile[ty + 8 * p][tx] = s2f(src[(size_t)b * sS + (size_t)(f0 + ty + 8 * p) * ldS + t0 + tx]);
    __syncthreads();
#pragma unroll
    for (int p = 0; p < 4; ++p)
        dst[(size_t)b * sD + (size_t)(t0 + ty + 8 * p) * ldD + f0 + tx] = tile[tx][ty + 8 * p];
}

// ---- MFMA GEMM (m97-style): C^T(N x M) = A(M x K, bf16) @ B^T(N x K, bf16) ----
// SPLIT>1: each z writes a PRIVATE f32 partial buffer at fOut + z*pstride (no atomics).
// vTout: for m0 >= 2048 (qkv V-third), write transposed to vTout[m-2048][n].
// qskip: skip blocks computing the dead Q-third x (t < 512) region of qkv.
template<int BN, int SPLIT>
__global__ __launch_bounds__(256) void gemm_bt(
    const u16* __restrict__ A,
    const u16* __restrict__ B,
    u16* __restrict__ C,
    float* __restrict__ fOut,
    int M, int K,
    const float* __restrict__ bias,
    int relu,
    int qskip,
    long pstride,
    u16* __restrict__ vTout)
{
    constexpr int BM = 128, BK = 64;
    constexpr int MI = (BN == 128) ? 4 : 2;
    constexpr int NI = 4;
    const int n0 = blockIdx.x * BN, m0 = blockIdx.y * BM;
    if (qskip && m0 + BM <= 1024 && (n0 & 1023) < 512) return;
    const int Ks = K / SPLIT;
    const int kbeg = blockIdx.z * Ks;
    __shared__ __align__(16) u16 As[BM * BK];
    __shared__ __align__(16) u16 Bs[BN * BK];
    const int tid = threadIdx.x, lane = tid & 63, wv = tid >> 6;
    const int l15 = lane & 15, quad = lane >> 4;
    const int wm = (BN == 128) ? (wv >> 1) * 64 : wv * 32;
    const int wn = (BN == 128) ? (wv & 1) * 64 : 0;
    f4v acc[MI][NI] = {};
    for (int kk = kbeg; kk < kbeg + Ks; kk += BK) {
        __syncthreads();
#pragma unroll
        for (int p = 0; p < (BM * 8) / 256; ++p) {
            int c = p * 256 + tid, r = c >> 3, q = c & 7, qs = q ^ (r & 7);
            gl2lds16(&A[(size_t)(m0 + r) * K + kk + qs * 8], &As[c * 8]);
        }
#pragma unroll
        for (int p = 0; p < (BN * 8) / 256; ++p) {
            int c = p * 256 + tid, r = c >> 3, q = c & 7, qs = q ^ (r & 7);
            gl2lds16(&B[(size_t)(n0 + r) * K + kk + qs * 8], &Bs[c * 8]);
        }
        __syncthreads();
#pragma unroll
        for (int k0 = 0; k0 < BK; k0 += 32) {
            s8v af[MI], bf[NI];
#pragma unroll
            for (int mi = 0; mi < MI; ++mi) {
                int r = wm + mi * 16 + l15;
                af[mi] = *(const s8v*)&As[r * BK + ((((k0 >> 3) + quad) ^ (r & 7)) << 3)];
            }
#pragma unroll
            for (int ni = 0; ni < NI; ++ni) {
                int r = wn + ni * 16 + l15;
                bf[ni] = *(const s8v*)&Bs[r * BK + ((((k0 >> 3) + quad) ^ (r & 7)) << 3)];
            }
#pragma unroll
            for (int mi = 0; mi < MI; ++mi)
#pragma unroll
                for (int ni = 0; ni < NI; ++ni)
                    acc[mi][ni] = __builtin_amdgcn_mfma_f32_16x16x32_bf16(af[mi], bf[ni], acc[mi][ni], 0, 0, 0);
        }
    }
    if (SPLIT > 1) {
        float* base = fOut + (long)blockIdx.z * pstride;
#pragma unroll
        for (int mi = 0; mi < MI; ++mi) {
            int m = m0 + wm + mi * 16 + quad * 4;
#pragma unroll
            for (int ni = 0; ni < NI; ++ni) {
                int n = n0 + wn + ni * 16 + l15;
                *(f4v*)&base[(size_t)n * M + m] = acc[mi][ni];   // plain 16B store, no RMW
            }
        }
    } else if (vTout && m0 >= 2048) {
        // V third of qkv: pure coalesced stores to V^T[d][n]
#pragma unroll
        for (int mi = 0; mi < MI; ++mi) {
            int m = m0 + wm + mi * 16 + quad * 4;
#pragma unroll
            for (int ni = 0; ni < NI; ++ni) {
                int n = n0 + wn + ni * 16 + l15;
#pragma unroll
                for (int r2 = 0; r2 < 4; ++r2)
                    vTout[(size_t)(m + r2 - 2048) * 4096 + n] = f2s(acc[mi][ni][r2]);
            }
        }
    } else {
#pragma unroll
        for (int mi = 0; mi < MI; ++mi) {
            int m = m0 + wm + mi * 16 + quad * 4;
            float bv[4] = {0.f, 0.f, 0.f, 0.f};
            if (bias) {
#pragma unroll
                for (int r2 = 0; r2 < 4; ++r2) bv[r2] = bias[m + r2];
            }
#pragma unroll
            for (int ni = 0; ni < NI; ++ni) {
                int n = n0 + wn + ni * 16 + l15;
                float o[4];
#pragma unroll
                for (int r2 = 0; r2 < 4; ++r2) o[r2] = acc[mi][ni][r2] + bv[r2];
                if (relu) {
#pragma unroll
                    for (int r2 = 0; r2 < 4; ++r2) o[r2] = fmaxf(o[r2], 0.f);
                }
                s4v st;
#pragma unroll
                for (int r2 = 0; r2 < 4; ++r2) st[r2] = (short)f2s(o[r2]);
                *(s4v*)&C[(size_t)n * M + m] = st;
            }
        }
    }
}

// ---- MFMA banded flash attention (v3: QT=32, direct-global K/V, LDS = S only) ----
// Shifted S: S[qi][t], t = j - (j0 + qi), t in [0,256). Two 16-row sets per block.
// K/R/V windows shared across 32 q rows (half the traffic of QT=16); V fragment
// loaded once and used by both row-sets' MFMAs. Window [j0-1, j0+287] fits klen
// exactly at QT=32 (i0 <= 480 -> j max 1023): no phase-4 clamp needed.
#define QT 32
#define SROW 260   // f32 row stride: 260 % 32 == 4 -> 2-way banks on row-indexed reads
__global__ __launch_bounds__(256, 4) void attn_mfma(
    const u16* __restrict__ WHT,      // (BSZ, KLEN, 3*DM) bf16 (Q,K thirds valid)
    const u16* __restrict__ VT,       // (DM, BSZ*KLEN) bf16 = V^T (+uss), cols n=b*1024+t
    const u16* __restrict__ RT,       // (WIN, DM) bf16
    const float* __restrict__ rwb, const float* __restrict__ rrb,
    u16* __restrict__ avT)            // (BSZ, QLEN, DM) bf16
{
    __shared__ __align__(16) float sS[QT * SROW];   // 33280 B total LDS

    const int qt = blockIdx.x, n = blockIdx.y, b = blockIdx.z;
    const int i0 = qt * QT, j0 = i0 + WIN + 1;
    const int tid = threadIdx.x, lane = tid & 63, wv = tid >> 6;
    const int l15 = lane & 15, quad = lane >> 4;
    const u16* W = WHT + (size_t)b * KLEN * (3 * DM);

    // Q fragments for both row-sets (A-operand rows = l15 = qi within set), biases baked in
    s8v qac[2][2], qbd[2][2];
#pragma unroll
    for (int h = 0; h < 2; ++h) {
        int qrow = MLEN + i0 + 16 * h + l15;
#pragma unroll
        for (int kc = 0; kc < 2; ++kc) {
            int col = n * DH + kc * 32 + quad * 8;
            s8v qv = *(const s8v*)&W[(size_t)qrow * (3 * DM) + col];
            s8v a, c;
#pragma unroll
            for (int e = 0; e < 8; ++e) {
                float qf = s2f((u16)qv[e]);
                a[e] = (short)f2s(qf + rwb[col + e]);
                c[e] = (short)f2s(qf + rrb[col + e]);
            }
            qac[h][kc] = a; qbd[h][kc] = c;
        }
    }

    // Phase 1: S[qi][t] = AC (QK^T); 18 k-tiles cover c in [0,288); j clamped (masked cells)
    for (int ci = wv; ci < 18; ci += 4) {
        int j = j0 + ci * 16 + l15; if (j > KLEN - 1) j = KLEN - 1;
        const u16* Kr = &W[(size_t)j * (3 * DM) + DM + n * DH + quad * 8];
        s8v k0 = *(const s8v*)Kr, k1 = *(const s8v*)(Kr + 32);
#pragma unroll
        for (int h = 0; h < 2; ++h) {
            f4v acc = {};
            acc = __builtin_amdgcn_mfma_f32_16x16x32_bf16(qac[h][0], k0, acc, 0, 0, 0);
            acc = __builtin_amdgcn_mfma_f32_16x16x32_bf16(qac[h][1], k1, acc, 0, 0, 0);
#pragma unroll
            for (int r2 = 0; r2 < 4; ++r2) {
                int qi = 16 * h + quad * 4 + r2;
                int t = ci * 16 + l15 - qi;
                if ((unsigned)t < 256u) sS[qi * SROW + t] = acc[r2];
            }
        }
    }
    __syncthreads();

    // Phase 2: S[qi][t'] += BD (rr_q @ R^T), R direct from global, unshifted in t'
#pragma unroll
    for (int cc = 0; cc < 4; ++cc) {
        int ci = wv + cc * 4;
        const u16* Rr = &RT[(size_t)(ci * 16 + l15) * DM + n * DH + quad * 8];
        s8v r0 = *(const s8v*)Rr, r1 = *(const s8v*)(Rr + 32);
#pragma unroll
        for (int h = 0; h < 2; ++h) {
            f4v acc = {};
            acc = __builtin_amdgcn_mfma_f32_16x16x32_bf16(qbd[h][0], r0, acc, 0, 0, 0);
            acc = __builtin_amdgcn_mfma_f32_16x16x32_bf16(qbd[h][1], r1, acc, 0, 0, 0);
#pragma unroll
            for (int r2 = 0; r2 < 4; ++r2) {
                int qi = 16 * h + quad * 4 + r2;
                sS[qi * SROW + ci * 16 + l15] += acc[r2];
            }
        }
    }
    __syncthreads();

    // Phase 3: softmax; 16-lane group g owns rows g and g+16. P (bf16) written in-place
    // over the row at c' = qi + 1 + t'; zeros at c' in [0,qi] and [qi+257,288).
    {
        int g = tid >> 4, l = tid & 15;
#pragma unroll
        for (int h = 0; h < 2; ++h) {
            int r = g + 16 * h;
            float vals[16], mx = -1e30f;
#pragma unroll
            for (int k = 0; k < 16; ++k) {
                float s = sS[r * SROW + l + 16 * k] * 0.125f;
                vals[k] = s; mx = fmaxf(mx, s);
            }
            asm volatile("" ::: "memory");   // fence: S f32 reads before u16 P writes (aliased)
#pragma unroll
            for (int d = 1; d < 16; d <<= 1) mx = fmaxf(mx, __shfl_xor(mx, d, 16));
            float sum = 0.f;
#pragma unroll
            for (int k = 0; k < 16; ++k) { vals[k] = __expf(vals[k] - mx); sum += vals[k]; }
#pragma unroll
            for (int d = 1; d < 16; d <<= 1) sum += __shfl_xor(sum, d, 16);
            float inv = 1.f / sum;
            u16* sPr = (u16*)&sS[r * SROW];
#pragma unroll
            for (int k = 0; k < 16; ++k) sPr[r + 1 + l + 16 * k] = f2s(vals[k] * inv);
            if (l <= r) sPr[l] = 0;                    // leading zeros [0, r]
            if (l + 16 <= r) sPr[l + 16] = 0;
            int p = r + 257 + l;                       // trailing zeros [r+257, 288)
            if (p < 288) sPr[p] = 0;
            p += 16;
            if (p < 288) sPr[p] = 0;
        }
    }
    __syncthreads();

    // Phase 4: O = P @ V; V fragment loaded once, used by both row-sets; 9 k-chunks
    const u16* sPu = (const u16*)sS;
    const size_t vbase = (size_t)(n * DH + wv * 16 + l15) * 4096
                       + (size_t)b * KLEN + (j0 - 1) + quad * 8;
    f4v o0 = {}, o1 = {};
#pragma unroll
    for (int kc = 0; kc < 9; ++kc) {
        s8v bb = *(const s8v*)&VT[vbase + kc * 32];
        s8v a0 = *(const s8v*)&sPu[(size_t)l15 * (2 * SROW) + kc * 32 + quad * 8];
        s8v a1 = *(const s8v*)&sPu[(size_t)(16 + l15) * (2 * SROW) + kc * 32 + quad * 8];
        o0 = __builtin_amdgcn_mfma_f32_16x16x32_bf16(a0, bb, o0, 0, 0, 0);
        o1 = __builtin_amdgcn_mfma_f32_16x16x32_bf16(a1, bb, o1, 0, 0, 0);
    }
#pragma unroll
    for (int r2 = 0; r2 < 4; ++r2) {
        int qi = quad * 4 + r2;
        avT[((size_t)b * QLEN + i0 + qi) * DM + n * DH + wv * 16 + l15] = f2s(o0[r2]);
        avT[((size_t)b * QLEN + i0 + 16 + qi) * DM + n * DH + wv * 16 + l15] = f2s(o1[r2]);
    }
}

// ---- layernorm: out = LN(sum of nparts partials + bias + res_bf16), row-contiguous ----
__global__ __launch_bounds__(256) void ln_f(
    const float* __restrict__ P, long pstride, int nparts,
    const float* __restrict__ bias,
    const u16* __restrict__ res, int resMode, u16* __restrict__ out)
{
    int n = blockIdx.x, tid = threadIdx.x;
    int lane = tid & 63, wv = tid >> 6;
    int f = tid * 4;
    int rrow = resMode ? (((n >> 9) * 2 + 1) * 512 + (n & 511)) : n;
    f4v pv = *(const f4v*)&P[(size_t)n * DM + f];
    for (int p = 1; p < nparts; ++p) {
        const float* Pp = P + (long)p * pstride;
        pv += *(const f4v*)&Pp[(size_t)n * DM + f];
    }
    s4v rv = *(const s4v*)&res[(size_t)rrow * DM + f];
    f4v bv = *(const f4v*)&bias[f];
    float v[4];
#pragma unroll
    for (int k = 0; k < 4; ++k) v[k] = pv[k] + bv[k] + s2f((u16)rv[k]);
    float s = v[0] + v[1] + v[2] + v[3];
    float ss = v[0] * v[0] + v[1] * v[1] + v[2] * v[2] + v[3] * v[3];
#pragma unroll
    for (int d = 1; d < 64; d <<= 1) {
        s += __shfl_xor(s, d, 64);
        ss += __shfl_xor(ss, d, 64);
    }
    __shared__ float ps[4], pss[4];
    if (lane == 0) { ps[wv] = s; pss[wv] = ss; }
    __syncthreads();
    float S = ps[0] + ps[1] + ps[2] + ps[3];
    float SS = pss[0] + pss[1] + pss[2] + pss[3];
    float m = S * (1.f / DM);
    float var = SS * (1.f / DM) - m * m;
    float inv = rsqrtf(fmaxf(var, 0.f) + 1e-5f);
    s4v st;
#pragma unroll
    for (int k = 0; k < 4; ++k) st[k] = (short)f2s((v[k] - m) * inv);
    *(s4v*)&out[(size_t)n * DM + f] = st;
}

extern "C" void kernel_launch(void* const* d_in, const int* in_sizes, int n_in,
                              void* d_out, int out_size, void* d_ws, size_t ws_size,
                              hipStream_t stream) {
    const float* z1ss  = (const float*)d_in[0];
    const float* uss   = (const float*)d_in[1];
    const float* z0    = (const float*)d_in[2];
    const float* pos   = (const float*)d_in[3];
    const float* qkv_w = (const float*)d_in[4];
    const float* r_w   = (const float*)d_in[5];
    const float* rwb   = (const float*)d_in[6];
    const float* rrb   = (const float*)d_in[7];
    const float* o_w   = (const float*)d_in[8];
    const float* o_b   = (const float*)d_in[9];
    const float* ff1_w = (const float*)d_in[10];
    const float* ff1_b = (const float*)d_in[11];
    const float* ff2_w = (const float*)d_in[12];
    const float* ff2_b = (const float*)d_in[13];

    u16* ws = (u16*)d_ws;
    u16* wQ   = ws;             // 3072x1024
    u16* wR   = ws + 3145728;
    u16* wO   = ws + 4194304;
    u16* wF1  = ws + 5242880;
    u16* wF2  = ws + 9437184;
    u16* catT = ws + 13631488;  // (4,1024,1024); later aliased as outT
    u16* whT  = ws + 17825792;  // (4,1024,3072); later aliased as hT
    u16* posT = ws + 30408704;  // (256,1024)
    u16* rT   = ws + 30670848;  // (256,1024)
    u16* avT  = ws + 30932992;  // (2048,1024)
    u16* xT   = ws + 33030144;  // (2048,1024)
    float* pref = (float*)(ws + 35127296);  // 2048x1024 f32  (split partial 0)
    u16* hT   = whT;
    u16* outT = catT;

    // vT (1024 x 4096 bf16, = 8 MB) aliases pref: live only between qkv gemm and attn;
    // pref is first written by o-proj (after attn).
    u16* vT = (u16*)pref;

    // split partial 1: workspace offset 0 (wQ+wR region, dead once o-proj/ff2 run)
    float* part1 = (float*)d_ws;
    long pstr = part1 - pref;   // negative f32-element stride between partials

    dim3 tblk(32, 8);

    conv_w5<<<13312, 256, 0, stream>>>(qkv_w, r_w, o_w, ff1_w, ff2_w,
                                       wQ, wR, wO, wF1, wF2);

    trans_f2b<<<dim3(16, 32, BSZ), tblk, 0, stream>>>(z0, (long)DM * MLEN, MLEN, 0,
                                                      catT, (long)KLEN * DM, DM, 0);
    trans_f2b<<<dim3(16, 32, BSZ), tblk, 0, stream>>>(z1ss, (long)DM * QLEN, QLEN, 0,
                                                      catT, (long)KLEN * DM, DM, MLEN);
    trans_f2b<<<dim3(8, 32, 1), tblk, 0, stream>>>(pos, 0, KLEN, KLEN - WIN,
                                                   posT, 0, DM, 0);

    // qkv: whT(4096 x 3072) = (qkv_w @ cat)^T for Q,K thirds; V third -> vT[d][n]
    // qskip=1: Q-third x (t<512) blocks are dead output -> early-exit (-17% FLOPs)
    gemm_bt<64, 1><<<dim3(64, 24, 1), 256, 0, stream>>>(
        wQ, catT, whT, nullptr, 3 * DM, DM, nullptr, 0, 1, 0, vT);

    // uss: Q/K thirds transpose-add into whT; V third straight-add into vT
    uss_add<<<dim3(32, 96, BSZ), tblk, 0, stream>>>(uss, whT, vT);

    // r: rT(256 x 1024) = (r_w @ pos[:,768:])^T
    gemm_bt<64, 1><<<dim3(4, 8, 1), 256, 0, stream>>>(
        wR, posT, rT, nullptr, DM, DM, nullptr, 0, 0, 0, nullptr);

    // MFMA banded attention -> avT  (QT=32: 1024 blocks, halved K/R/V traffic)
    attn_mfma<<<dim3(QLEN / QT, NH, BSZ), 256, 0, stream>>>(whT, vT, rT, rwb, rrb, avT);

    // o-proj split-2, private partials (overwrites pref/vT: attn already consumed vT)
    gemm_bt<64, 2><<<dim3(32, 8, 2), 256, 0, stream>>>(
        wO, avT, nullptr, pref, DM, DM, nullptr, 0, 0, pstr, nullptr);

    ln_f<<<2048, 256, 0, stream>>>(pref, pstr, 2, o_b, catT, 1, xT);

    // ff1  (BN=64)
    gemm_bt<64, 1><<<dim3(32, 32, 1), 256, 0, stream>>>(
        wF1, xT, hT, nullptr, DI, DM, ff1_b, 1, 0, 0, nullptr);

    // ff2 split-2, private partials
    gemm_bt<64, 2><<<dim3(32, 8, 2), 256, 0, stream>>>(
        wF2, hT, nullptr, pref, DM, DI, nullptr, 0, 0, pstr, nullptr);

    ln_f<<<2048, 256, 0, stream>>>(pref, pstr, 2, ff2_b, xT, 0, outT);

    trans_b2f<<<dim3(32, 16, BSZ), tblk, 0, stream>>>(outT, (long)QLEN * DM, DM,
                                                      (float*)d_out, (long)DM * QLEN, QLEN);
}

// Round 7
// 325.914 us; speedup vs baseline: 1.0948x; 1.0355x over previous
//
#include <hip/hip_runtime.h>
#include <hip/hip_bf16.h>

typedef unsigned short u16;
typedef __attribute__((ext_vector_type(8))) short s8v;
typedef __attribute__((ext_vector_type(4))) short s4v;
typedef __attribute__((ext_vector_type(4))) float f4v;

__device__ __forceinline__ float s2f(u16 s) {
    unsigned int u = ((unsigned int)s) << 16;
    return __builtin_bit_cast(float, u);
}
__device__ __forceinline__ u16 f2s(float f) {
    __hip_bfloat16 h = __float2bfloat16(f);
    return __builtin_bit_cast(u16, h);
}

// async global->LDS DMA, 16 B per lane; LDS dst must be lane-linear
__device__ __forceinline__ void gl2lds16(const u16* g, u16* l) {
    __builtin_amdgcn_global_load_lds((const __attribute__((address_space(1))) void*)g,
                                     (__attribute__((address_space(3))) void*)l, 16, 0, 0);
}

#define BSZ 4
#define DM 1024
#define QLEN 512
#define MLEN 512
#define KLEN 1024
#define DI 4096
#define NH 16
#define DH 64
#define WIN 256   // valid keys: j = i+257 .. i+512 (exactly 256 per query, never clipped)

// ---- fused prep: weight f32->bf16 conversion + z0/z1ss/pos transposes (1 launch) ----
// block ranges: [0,13312) conv; [13312,15360) z0; [15360,17408) z1ss; [17408,17664) pos
#define CONV_BLKS 13312
#define Z0_BLKS 2048
#define Z1_BLKS 2048
#define POS_BLKS 256
__global__ __launch_bounds__(256) void prep(
    const float* __restrict__ qkv_w, const float* __restrict__ r_w,
    const float* __restrict__ o_w, const float* __restrict__ ff1_w,
    const float* __restrict__ ff2_w,
    u16* __restrict__ wQ, u16* __restrict__ wR, u16* __restrict__ wO,
    u16* __restrict__ wF1, u16* __restrict__ wF2,
    const float* __restrict__ z0, const float* __restrict__ z1ss,
    const float* __restrict__ pos,
    u16* __restrict__ catT, u16* __restrict__ posT)
{
    int bx = blockIdx.x, tid = threadIdx.x;
    if (bx < CONV_BLKS) {
        const int e0 = 786432, e1 = e0 + 262144, e2 = e1 + 262144, e3 = e2 + 1048576;
        int i = bx * 256 + tid;
        const float* s; u16* d; int off;
        if (i < e0)      { s = qkv_w; d = wQ;  off = i; }
        else if (i < e1) { s = r_w;   d = wR;  off = i - e0; }
        else if (i < e2) { s = o_w;   d = wO;  off = i - e1; }
        else if (i < e3) { s = ff1_w; d = wF1; off = i - e2; }
        else             { s = ff2_w; d = wF2; off = i - e3; }
        f4v v = *(const f4v*)&s[(size_t)off * 4];
        s4v o;
#pragma unroll
        for (int k = 0; k < 4; ++k) o[k] = (short)f2s(v[k]);
        *(s4v*)&d[(size_t)off * 4] = o;
        return;
    }
    __shared__ float tile[32][33];
    int tx = tid & 31, ty = tid >> 5;   // (32, 8)
    const float* src; u16* dst; long sS, sD; int ldS, ldD, colOff, rowOff, t0, f0, b;
    if (bx < CONV_BLKS + Z0_BLKS) {
        int idx = bx - CONV_BLKS;
        t0 = (idx & 15) * 32; f0 = ((idx >> 4) & 31) * 32; b = idx >> 9;
        src = z0;   sS = (long)DM * MLEN; ldS = MLEN; colOff = 0;
        dst = catT; sD = (long)KLEN * DM; ldD = DM;  rowOff = 0;
    } else if (bx < CONV_BLKS + Z0_BLKS + Z1_BLKS) {
        int idx = bx - CONV_BLKS - Z0_BLKS;
        t0 = (idx & 15) * 32; f0 = ((idx >> 4) & 31) * 32; b = idx >> 9;
        src = z1ss; sS = (long)DM * QLEN; ldS = QLEN; colOff = 0;
        dst = catT; sD = (long)KLEN * DM; ldD = DM;  rowOff = MLEN;
    } else {
        int idx = bx - CONV_BLKS - Z0_BLKS - Z1_BLKS;
        t0 = (idx & 7) * 32; f0 = (idx >> 3) * 32; b = 0;
        src = pos;  sS = 0; ldS = KLEN; colOff = KLEN - WIN;
        dst = posT; sD = 0; ldD = DM;   rowOff = 0;
    }
#pragma unroll
    for (int p = 0; p < 4; ++p)
        tile[ty + 8 * p][tx] = src[(size_t)b * sS + (size_t)(f0 + ty + 8 * p) * ldS + colOff + t0 + tx];
    __syncthreads();
#pragma unroll
    for (int p = 0; p < 4; ++p)
        dst[(size_t)b * sD + (size_t)(rowOff + t0 + ty + 8 * p) * ldD + f0 + tx] = f2s(tile[tx][ty + 8 * p]);
}

// ---- uss add: Q/K thirds transpose-add into whT; V third straight-add into vT ----
// y < 64 : whT[b][t][f0+..] += uss[b][f0+..][t]^T   (LDS 32x33 transpose)
// y >= 64: vT[d][b*1024+t]  += uss[b][2048+d][t]    (same layout, no transpose)
// Q-third (fy<32) only needed for t >= 512 (w_head_q takes last qlen positions).
__global__ __launch_bounds__(256) void uss_add(
    const float* __restrict__ uss, u16* __restrict__ whT, u16* __restrict__ vT)
{
    __shared__ float tile[32][33];
    int b = blockIdx.z;
    int t0 = blockIdx.x * 32, fy = blockIdx.y;
    int tx = threadIdx.x, ty = threadIdx.y;   // (32, 8)
    if (fy < 32 && t0 < 512) return;          // dead Q-third region
    const float* S = uss + (size_t)b * 3072 * 1024;
    if (fy < 64) {
        int f0 = fy * 32;
        u16* D = whT + (size_t)b * 1024 * 3072;
#pragma unroll
        for (int p = 0; p < 4; ++p)
            tile[ty + 8 * p][tx] = S[(size_t)(f0 + ty + 8 * p) * 1024 + t0 + tx];
        __syncthreads();
#pragma unroll
        for (int p = 0; p < 4; ++p) {
            size_t o = (size_t)(t0 + ty + 8 * p) * 3072 + f0 + tx;
            D[o] = f2s(s2f(D[o]) + tile[tx][ty + 8 * p]);
        }
    } else {
        int d0 = (fy - 64) * 32;
#pragma unroll
        for (int p = 0; p < 4; ++p) {
            int d = d0 + ty + 8 * p;
            size_t ui = ((size_t)2048 + d) * 1024 + t0 + tx;
            size_t vi = (size_t)d * 4096 + (size_t)b * KLEN + t0 + tx;
            vT[vi] = f2s(s2f(vT[vi]) + S[ui]);
        }
    }
}

// ---- transpose bf16 (position-major) -> f32 (feature-major) ----
__global__ __launch_bounds__(256) void trans_b2f(
    const u16* __restrict__ src, long sS, int ldS,
    float* __restrict__ dst, long sD, int ldD)
{
    __shared__ float tile[32][33];
    int b = blockIdx.z;
    int t0 = blockIdx.x * 32, f0 = blockIdx.y * 32;
    int tx = threadIdx.x, ty = threadIdx.y;
#pragma unroll
    for (int p = 0; p < 4; ++p)
        tile[ty + 8 * p][tx] = s2f(src[(size_t)b * sS + (size_t)(f0 + ty + 8 * p) * ldS + t0 + tx]);
    __syncthreads();
#pragma unroll
    for (int p = 0; p < 4; ++p)
        dst[(size_t)b * sD + (size_t)(t0 + ty + 8 * p) * ldD + f0 + tx] = tile[tx][ty + 8 * p];
}

// ---- MFMA GEMM (m97-style): C^T(N x M) = A(M x K, bf16) @ B^T(N x K, bf16) ----
// SPLIT>1: each z writes a PRIVATE f32 partial buffer at fOut + z*pstride (no atomics).
// vTout: for m0 >= 2048 (qkv V-third), write transposed to vTout[m-2048][n].
// qskip: skip blocks computing the dead Q-third x (t < 512) region of qkv.
template<int BN, int SPLIT>
__global__ __launch_bounds__(256) void gemm_bt(
    const u16* __restrict__ A,
    const u16* __restrict__ B,
    u16* __restrict__ C,
    float* __restrict__ fOut,
    int M, int K,
    const float* __restrict__ bias,
    int relu,
    int qskip,
    long pstride,
    u16* __restrict__ vTout)
{
    constexpr int BM = 128, BK = 64;
    constexpr int MI = (BN == 128) ? 4 : 2;
    constexpr int NI = 4;
    const int n0 = blockIdx.x * BN, m0 = blockIdx.y * BM;
    if (qskip && m0 + BM <= 1024 && (n0 & 1023) < 512) return;
    const int Ks = K / SPLIT;
    const int kbeg = blockIdx.z * Ks;
    __shared__ __align__(16) u16 As[BM * BK];
    __shared__ __align__(16) u16 Bs[BN * BK];
    const int tid = threadIdx.x, lane = tid & 63, wv = tid >> 6;
    const int l15 = lane & 15, quad = lane >> 4;
    const int wm = (BN == 128) ? (wv >> 1) * 64 : wv * 32;
    const int wn = (BN == 128) ? (wv & 1) * 64 : 0;
    f4v acc[MI][NI] = {};
    for (int kk = kbeg; kk < kbeg + Ks; kk += BK) {
        __syncthreads();
#pragma unroll
        for (int p = 0; p < (BM * 8) / 256; ++p) {
            int c = p * 256 + tid, r = c >> 3, q = c & 7, qs = q ^ (r & 7);
            gl2lds16(&A[(size_t)(m0 + r) * K + kk + qs * 8], &As[c * 8]);
        }
#pragma unroll
        for (int p = 0; p < (BN * 8) / 256; ++p) {
            int c = p * 256 + tid, r = c >> 3, q = c & 7, qs = q ^ (r & 7);
            gl2lds16(&B[(size_t)(n0 + r) * K + kk + qs * 8], &Bs[c * 8]);
        }
        __syncthreads();
#pragma unroll
        for (int k0 = 0; k0 < BK; k0 += 32) {
            s8v af[MI], bf[NI];
#pragma unroll
            for (int mi = 0; mi < MI; ++mi) {
                int r = wm + mi * 16 + l15;
                af[mi] = *(const s8v*)&As[r * BK + ((((k0 >> 3) + quad) ^ (r & 7)) << 3)];
            }
#pragma unroll
            for (int ni = 0; ni < NI; ++ni) {
                int r = wn + ni * 16 + l15;
                bf[ni] = *(const s8v*)&Bs[r * BK + ((((k0 >> 3) + quad) ^ (r & 7)) << 3)];
            }
#pragma unroll
            for (int mi = 0; mi < MI; ++mi)
#pragma unroll
                for (int ni = 0; ni < NI; ++ni)
                    acc[mi][ni] = __builtin_amdgcn_mfma_f32_16x16x32_bf16(af[mi], bf[ni], acc[mi][ni], 0, 0, 0);
        }
    }
    if (SPLIT > 1) {
        float* base = fOut + (long)blockIdx.z * pstride;
#pragma unroll
        for (int mi = 0; mi < MI; ++mi) {
            int m = m0 + wm + mi * 16 + quad * 4;
#pragma unroll
            for (int ni = 0; ni < NI; ++ni) {
                int n = n0 + wn + ni * 16 + l15;
                *(f4v*)&base[(size_t)n * M + m] = acc[mi][ni];   // plain 16B store, no RMW
            }
        }
    } else if (vTout && m0 >= 2048) {
        // V third of qkv: pure coalesced stores to V^T[d][n]
#pragma unroll
        for (int mi = 0; mi < MI; ++mi) {
            int m = m0 + wm + mi * 16 + quad * 4;
#pragma unroll
            for (int ni = 0; ni < NI; ++ni) {
                int n = n0 + wn + ni * 16 + l15;
#pragma unroll
                for (int r2 = 0; r2 < 4; ++r2)
                    vTout[(size_t)(m + r2 - 2048) * 4096 + n] = f2s(acc[mi][ni][r2]);
            }
        }
    } else {
#pragma unroll
        for (int mi = 0; mi < MI; ++mi) {
            int m = m0 + wm + mi * 16 + quad * 4;
            float bv[4] = {0.f, 0.f, 0.f, 0.f};
            if (bias) {
#pragma unroll
                for (int r2 = 0; r2 < 4; ++r2) bv[r2] = bias[m + r2];
            }
#pragma unroll
            for (int ni = 0; ni < NI; ++ni) {
                int n = n0 + wn + ni * 16 + l15;
                float o[4];
#pragma unroll
                for (int r2 = 0; r2 < 4; ++r2) o[r2] = acc[mi][ni][r2] + bv[r2];
                if (relu) {
#pragma unroll
                    for (int r2 = 0; r2 < 4; ++r2) o[r2] = fmaxf(o[r2], 0.f);
                }
                s4v st;
#pragma unroll
                for (int r2 = 0; r2 < 4; ++r2) st[r2] = (short)f2s(o[r2]);
                *(s4v*)&C[(size_t)n * M + m] = st;
            }
        }
    }
}

// ---- MFMA banded flash attention (v4: QT=64, direct-global K/V, LDS = S only) ----
// Shifted S: S[qi][t], t = j - (j0 + qi), t in [0,256). Four 16-row sets per block.
// K/R windows shared across 64 q rows; V fragment loaded once, used by all 4 sets.
// P padded to 320 k-cols (QT+256) -> 10 clean chunks; V window ends exactly at klen-1
// for the last tile (i0=448: j0-1+319 = 1023) -> no clamp in phase 4.
#define QT 64
#define SROW 260   // f32 row stride: 260 % 32 == 4 -> spreads rows across banks
__global__ __launch_bounds__(256, 2) void attn_mfma(
    const u16* __restrict__ WHT,      // (BSZ, KLEN, 3*DM) bf16 (Q,K thirds valid)
    const u16* __restrict__ VT,       // (DM, BSZ*KLEN) bf16 = V^T (+uss), cols n=b*1024+t
    const u16* __restrict__ RT,       // (WIN, DM) bf16
    const float* __restrict__ rwb, const float* __restrict__ rrb,
    u16* __restrict__ avT)            // (BSZ, QLEN, DM) bf16
{
    __shared__ __align__(16) float sS[QT * SROW];   // 66560 B -> 2 blocks/CU

    const int qt = blockIdx.x, n = blockIdx.y, b = blockIdx.z;
    const int i0 = qt * QT, j0 = i0 + WIN + 1;
    const int tid = threadIdx.x, lane = tid & 63, wv = tid >> 6;
    const int l15 = lane & 15, quad = lane >> 4;
    const u16* W = WHT + (size_t)b * KLEN * (3 * DM);

    // Q fragments for 4 row-sets (A-operand rows = l15 = qi within set), biases baked in
    s8v qac[4][2], qbd[4][2];
#pragma unroll
    for (int h = 0; h < 4; ++h) {
        int qrow = MLEN + i0 + 16 * h + l15;
#pragma unroll
        for (int kc = 0; kc < 2; ++kc) {
            int col = n * DH + kc * 32 + quad * 8;
            s8v qv = *(const s8v*)&W[(size_t)qrow * (3 * DM) + col];
            s8v a, c;
#pragma unroll
            for (int e = 0; e < 8; ++e) {
                float qf = s2f((u16)qv[e]);
                a[e] = (short)f2s(qf + rwb[col + e]);
                c[e] = (short)f2s(qf + rrb[col + e]);
            }
            qac[h][kc] = a; qbd[h][kc] = c;
        }
    }

    // Phase 1: S[qi][t] = AC (QK^T); 20 k-tiles cover c in [0,320); j clamped only at the
    // very last tile row (garbage never stored: t >= 256 there)
    for (int ci = wv; ci < 20; ci += 4) {
        int j = j0 + ci * 16 + l15; if (j > KLEN - 1) j = KLEN - 1;
        const u16* Kr = &W[(size_t)j * (3 * DM) + DM + n * DH + quad * 8];
        s8v k0 = *(const s8v*)Kr, k1 = *(const s8v*)(Kr + 32);
#pragma unroll
        for (int h = 0; h < 4; ++h) {
            f4v acc = {};
            acc = __builtin_amdgcn_mfma_f32_16x16x32_bf16(qac[h][0], k0, acc, 0, 0, 0);
            acc = __builtin_amdgcn_mfma_f32_16x16x32_bf16(qac[h][1], k1, acc, 0, 0, 0);
#pragma unroll
            for (int r2 = 0; r2 < 4; ++r2) {
                int qi = 16 * h + quad * 4 + r2;
                int t = ci * 16 + l15 - qi;
                if ((unsigned)t < 256u) sS[qi * SROW + t] = acc[r2];
            }
        }
    }
    __syncthreads();

    // Phase 2: S[qi][t'] += BD (rr_q @ R^T), R direct from global, unshifted in t'
#pragma unroll
    for (int cc = 0; cc < 4; ++cc) {
        int ci = wv + cc * 4;
        const u16* Rr = &RT[(size_t)(ci * 16 + l15) * DM + n * DH + quad * 8];
        s8v r0 = *(const s8v*)Rr, r1 = *(const s8v*)(Rr + 32);
#pragma unroll
        for (int h = 0; h < 4; ++h) {
            f4v acc = {};
            acc = __builtin_amdgcn_mfma_f32_16x16x32_bf16(qbd[h][0], r0, acc, 0, 0, 0);
            acc = __builtin_amdgcn_mfma_f32_16x16x32_bf16(qbd[h][1], r1, acc, 0, 0, 0);
#pragma unroll
            for (int r2 = 0; r2 < 4; ++r2) {
                int qi = 16 * h + quad * 4 + r2;
                sS[qi * SROW + ci * 16 + l15] += acc[r2];
            }
        }
    }
    __syncthreads();

    // Phase 3: softmax; 16-lane group g owns rows g+16h. P (bf16) written in-place over
    // the row at c' = qi + 1 + t'; zeros at c' in [0,qi] and [qi+257,320).
    {
        int g = tid >> 4, l = tid & 15;
#pragma unroll
        for (int h = 0; h < 4; ++h) {
            int r = g + 16 * h;
            float vals[16], mx = -1e30f;
#pragma unroll
            for (int k = 0; k < 16; ++k) {
                float s = sS[r * SROW + l + 16 * k] * 0.125f;
                vals[k] = s; mx = fmaxf(mx, s);
            }
            asm volatile("" ::: "memory");   // fence: S f32 reads before u16 P writes (aliased)
#pragma unroll
            for (int d = 1; d < 16; d <<= 1) mx = fmaxf(mx, __shfl_xor(mx, d, 16));
            float sum = 0.f;
#pragma unroll
            for (int k = 0; k < 16; ++k) { vals[k] = __expf(vals[k] - mx); sum += vals[k]; }
#pragma unroll
            for (int d = 1; d < 16; d <<= 1) sum += __shfl_xor(sum, d, 16);
            float inv = 1.f / sum;
            u16* sPr = (u16*)&sS[r * SROW];
#pragma unroll
            for (int k = 0; k < 16; ++k) sPr[r + 1 + l + 16 * k] = f2s(vals[k] * inv);
            for (int p = l; p <= r; p += 16) sPr[p] = 0;               // leading zeros [0, r]
            for (int p = r + 257 + l; p < 320; p += 16) sPr[p] = 0;    // trailing [r+257, 320)
        }
    }
    __syncthreads();

    // Phase 4: O = P @ V; V fragment loaded once, used by all 4 row-sets; 10 k-chunks
    const u16* sPu = (const u16*)sS;
    const size_t vbase = (size_t)(n * DH + wv * 16 + l15) * 4096
                       + (size_t)b * KLEN + (j0 - 1) + quad * 8;
    f4v o[4] = {};
#pragma unroll
    for (int kc = 0; kc < 10; ++kc) {
        s8v bb = *(const s8v*)&VT[vbase + kc * 32];
#pragma unroll
        for (int h = 0; h < 4; ++h) {
            s8v a = *(const s8v*)&sPu[(size_t)(16 * h + l15) * (2 * SROW) + kc * 32 + quad * 8];
            o[h] = __builtin_amdgcn_mfma_f32_16x16x32_bf16(a, bb, o[h], 0, 0, 0);
        }
    }
#pragma unroll
    for (int h = 0; h < 4; ++h)
#pragma unroll
        for (int r2 = 0; r2 < 4; ++r2) {
            int qi = quad * 4 + r2;
            avT[((size_t)b * QLEN + i0 + 16 * h + qi) * DM + n * DH + wv * 16 + l15] = f2s(o[h][r2]);
        }
}

// ---- layernorm: out = LN(sum of nparts partials + bias + res_bf16), row-contiguous ----
__global__ __launch_bounds__(256) void ln_f(
    const float* __restrict__ P, long pstride, int nparts,
    const float* __restrict__ bias,
    const u16* __restrict__ res, int resMode, u16* __restrict__ out)
{
    int n = blockIdx.x, tid = threadIdx.x;
    int lane = tid & 63, wv = tid >> 6;
    int f = tid * 4;
    int rrow = resMode ? (((n >> 9) * 2 + 1) * 512 + (n & 511)) : n;
    f4v pv = *(const f4v*)&P[(size_t)n * DM + f];
    for (int p = 1; p < nparts; ++p) {
        const float* Pp = P + (long)p * pstride;
        pv += *(const f4v*)&Pp[(size_t)n * DM + f];
    }
    s4v rv = *(const s4v*)&res[(size_t)rrow * DM + f];
    f4v bv = *(const f4v*)&bias[f];
    float v[4];
#pragma unroll
    for (int k = 0; k < 4; ++k) v[k] = pv[k] + bv[k] + s2f((u16)rv[k]);
    float s = v[0] + v[1] + v[2] + v[3];
    float ss = v[0] * v[0] + v[1] * v[1] + v[2] * v[2] + v[3] * v[3];
#pragma unroll
    for (int d = 1; d < 64; d <<= 1) {
        s += __shfl_xor(s, d, 64);
        ss += __shfl_xor(ss, d, 64);
    }
    __shared__ float ps[4], pss[4];
    if (lane == 0) { ps[wv] = s; pss[wv] = ss; }
    __syncthreads();
    float S = ps[0] + ps[1] + ps[2] + ps[3];
    float SS = pss[0] + pss[1] + pss[2] + pss[3];
    float m = S * (1.f / DM);
    float var = SS * (1.f / DM) - m * m;
    float inv = rsqrtf(fmaxf(var, 0.f) + 1e-5f);
    s4v st;
#pragma unroll
    for (int k = 0; k < 4; ++k) st[k] = (short)f2s((v[k] - m) * inv);
    *(s4v*)&out[(size_t)n * DM + f] = st;
}

extern "C" void kernel_launch(void* const* d_in, const int* in_sizes, int n_in,
                              void* d_out, int out_size, void* d_ws, size_t ws_size,
                              hipStream_t stream) {
    const float* z1ss  = (const float*)d_in[0];
    const float* uss   = (const float*)d_in[1];
    const float* z0    = (const float*)d_in[2];
    const float* pos   = (const float*)d_in[3];
    const float* qkv_w = (const float*)d_in[4];
    const float* r_w   = (const float*)d_in[5];
    const float* rwb   = (const float*)d_in[6];
    const float* rrb   = (const float*)d_in[7];
    const float* o_w   = (const float*)d_in[8];
    const float* o_b   = (const float*)d_in[9];
    const float* ff1_w = (const float*)d_in[10];
    const float* ff1_b = (const float*)d_in[11];
    const float* ff2_w = (const float*)d_in[12];
    const float* ff2_b = (const float*)d_in[13];

    u16* ws = (u16*)d_ws;
    u16* wQ   = ws;             // 3072x1024
    u16* wR   = ws + 3145728;
    u16* wO   = ws + 4194304;
    u16* wF1  = ws + 5242880;
    u16* wF2  = ws + 9437184;
    u16* catT = ws + 13631488;  // (4,1024,1024); later aliased as outT
    u16* whT  = ws + 17825792;  // (4,1024,3072); later aliased as hT
    u16* posT = ws + 30408704;  // (256,1024)
    u16* rT   = ws + 30670848;  // (256,1024)
    u16* avT  = ws + 30932992;  // (2048,1024)
    u16* xT   = ws + 33030144;  // (2048,1024)
    float* pref = (float*)(ws + 35127296);  // 2048x1024 f32  (split partial 0)
    u16* hT   = whT;
    u16* outT = catT;

    // vT (1024 x 4096 bf16, = 8 MB) aliases pref: live only between qkv gemm and attn;
    // pref is first written by o-proj (after attn).
    u16* vT = (u16*)pref;

    // split partial 1: workspace offset 0 (wQ+wR region, dead once o-proj/ff2 run)
    float* part1 = (float*)d_ws;
    long pstr = part1 - pref;   // negative f32-element stride between partials

    dim3 tblk(32, 8);

    // fused weight-convert + input transposes (replaces 4 launches)
    prep<<<CONV_BLKS + Z0_BLKS + Z1_BLKS + POS_BLKS, 256, 0, stream>>>(
        qkv_w, r_w, o_w, ff1_w, ff2_w, wQ, wR, wO, wF1, wF2,
        z0, z1ss, pos, catT, posT);

    // qkv: whT(4096 x 3072) = (qkv_w @ cat)^T for Q,K thirds; V third -> vT[d][n]
    // qskip=1: Q-third x (t<512) blocks are dead output -> early-exit (-17% FLOPs)
    gemm_bt<64, 1><<<dim3(64, 24, 1), 256, 0, stream>>>(
        wQ, catT, whT, nullptr, 3 * DM, DM, nullptr, 0, 1, 0, vT);

    // uss: Q/K thirds transpose-add into whT; V third straight-add into vT
    uss_add<<<dim3(32, 96, BSZ), tblk, 0, stream>>>(uss, whT, vT);

    // r: rT(256 x 1024) = (r_w @ pos[:,768:])^T
    gemm_bt<64, 1><<<dim3(4, 8, 1), 256, 0, stream>>>(
        wR, posT, rT, nullptr, DM, DM, nullptr, 0, 0, 0, nullptr);

    // MFMA banded attention -> avT  (QT=64: 512 blocks, 2/CU, halved window traffic)
    attn_mfma<<<dim3(QLEN / QT, NH, BSZ), 256, 0, stream>>>(whT, vT, rT, rwb, rrb, avT);

    // o-proj split-2, private partials (overwrites pref/vT: attn already consumed vT)
    gemm_bt<64, 2><<<dim3(32, 8, 2), 256, 0, stream>>>(
        wO, avT, nullptr, pref, DM, DM, nullptr, 0, 0, pstr, nullptr);

    ln_f<<<2048, 256, 0, stream>>>(pref, pstr, 2, o_b, catT, 1, xT);

    // ff1  (BN=64)
    gemm_bt<64, 1><<<dim3(32, 32, 1), 256, 0, stream>>>(
        wF1, xT, hT, nullptr, DI, DM, ff1_b, 1, 0, 0, nullptr);

    // ff2 split-2, private partials
    gemm_bt<64, 2><<<dim3(32, 8, 2), 256, 0, stream>>>(
        wF2, hT, nullptr, pref, DM, DI, nullptr, 0, 0, pstr, nullptr);

    ln_f<<<2048, 256, 0, stream>>>(pref, pstr, 2, ff2_b, xT, 0, outT);

    trans_b2f<<<dim3(32, 16, BSZ), tblk, 0, stream>>>(outT, (long)QLEN * DM, DM,
                                                      (float*)d_out, (long)DM * QLEN, QLEN);
}

// Round 8
// 318.514 us; speedup vs baseline: 1.1202x; 1.0232x over previous
//
#include <hip/hip_runtime.h>
#include <hip/hip_bf16.h>

typedef unsigned short u16;
typedef __attribute__((ext_vector_type(8))) short s8v;
typedef __attribute__((ext_vector_type(4))) short s4v;
typedef __attribute__((ext_vector_type(4))) float f4v;

__device__ __forceinline__ float s2f(u16 s) {
    unsigned int u = ((unsigned int)s) << 16;
    return __builtin_bit_cast(float, u);
}
__device__ __forceinline__ u16 f2s(float f) {
    __hip_bfloat16 h = __float2bfloat16(f);
    return __builtin_bit_cast(u16, h);
}

// async global->LDS DMA, 16 B per lane; LDS dst must be lane-linear
__device__ __forceinline__ void gl2lds16(const u16* g, u16* l) {
    __builtin_amdgcn_global_load_lds((const __attribute__((address_space(1))) void*)g,
                                     (__attribute__((address_space(3))) void*)l, 16, 0, 0);
}

#define BSZ 4
#define DM 1024
#define QLEN 512
#define MLEN 512
#define KLEN 1024
#define DI 4096
#define NH 16
#define DH 64
#define WIN 256   // valid keys: j = i+257 .. i+512 (exactly 256 per query, never clipped)

// ---- fused prep: weight f32->bf16 conversion + z0/z1ss/pos transposes (1 launch) ----
#define CONV_BLKS 13312
#define Z0_BLKS 2048
#define Z1_BLKS 2048
#define POS_BLKS 256
__global__ __launch_bounds__(256) void prep(
    const float* __restrict__ qkv_w, const float* __restrict__ r_w,
    const float* __restrict__ o_w, const float* __restrict__ ff1_w,
    const float* __restrict__ ff2_w,
    u16* __restrict__ wQ, u16* __restrict__ wR, u16* __restrict__ wO,
    u16* __restrict__ wF1, u16* __restrict__ wF2,
    const float* __restrict__ z0, const float* __restrict__ z1ss,
    const float* __restrict__ pos,
    u16* __restrict__ catT, u16* __restrict__ posT)
{
    int bx = blockIdx.x, tid = threadIdx.x;
    if (bx < CONV_BLKS) {
        const int e0 = 786432, e1 = e0 + 262144, e2 = e1 + 262144, e3 = e2 + 1048576;
        int i = bx * 256 + tid;
        const float* s; u16* d; int off;
        if (i < e0)      { s = qkv_w; d = wQ;  off = i; }
        else if (i < e1) { s = r_w;   d = wR;  off = i - e0; }
        else if (i < e2) { s = o_w;   d = wO;  off = i - e1; }
        else if (i < e3) { s = ff1_w; d = wF1; off = i - e2; }
        else             { s = ff2_w; d = wF2; off = i - e3; }
        f4v v = *(const f4v*)&s[(size_t)off * 4];
        s4v o;
#pragma unroll
        for (int k = 0; k < 4; ++k) o[k] = (short)f2s(v[k]);
        *(s4v*)&d[(size_t)off * 4] = o;
        return;
    }
    __shared__ float tile[32][33];
    int tx = tid & 31, ty = tid >> 5;   // (32, 8)
    const float* src; u16* dst; long sS, sD; int ldS, ldD, colOff, rowOff, t0, f0, b;
    if (bx < CONV_BLKS + Z0_BLKS) {
        int idx = bx - CONV_BLKS;
        t0 = (idx & 15) * 32; f0 = ((idx >> 4) & 31) * 32; b = idx >> 9;
        src = z0;   sS = (long)DM * MLEN; ldS = MLEN; colOff = 0;
        dst = catT; sD = (long)KLEN * DM; ldD = DM;  rowOff = 0;
    } else if (bx < CONV_BLKS + Z0_BLKS + Z1_BLKS) {
        int idx = bx - CONV_BLKS - Z0_BLKS;
        t0 = (idx & 15) * 32; f0 = ((idx >> 4) & 31) * 32; b = idx >> 9;
        src = z1ss; sS = (long)DM * QLEN; ldS = QLEN; colOff = 0;
        dst = catT; sD = (long)KLEN * DM; ldD = DM;  rowOff = MLEN;
    } else {
        int idx = bx - CONV_BLKS - Z0_BLKS - Z1_BLKS;
        t0 = (idx & 7) * 32; f0 = (idx >> 3) * 32; b = 0;
        src = pos;  sS = 0; ldS = KLEN; colOff = KLEN - WIN;
        dst = posT; sD = 0; ldD = DM;   rowOff = 0;
    }
#pragma unroll
    for (int p = 0; p < 4; ++p)
        tile[ty + 8 * p][tx] = src[(size_t)b * sS + (size_t)(f0 + ty + 8 * p) * ldS + colOff + t0 + tx];
    __syncthreads();
#pragma unroll
    for (int p = 0; p < 4; ++p)
        dst[(size_t)b * sD + (size_t)(rowOff + t0 + ty + 8 * p) * ldD + f0 + tx] = f2s(tile[tx][ty + 8 * p]);
}

// ---- uss add: Q/K thirds transpose-add into whT; V third straight-add into vT ----
__global__ __launch_bounds__(256) void uss_add(
    const float* __restrict__ uss, u16* __restrict__ whT, u16* __restrict__ vT)
{
    __shared__ float tile[32][33];
    int b = blockIdx.z;
    int t0 = blockIdx.x * 32, fy = blockIdx.y;
    int tx = threadIdx.x, ty = threadIdx.y;   // (32, 8)
    if (fy < 32 && t0 < 512) return;          // dead Q-third region
    const float* S = uss + (size_t)b * 3072 * 1024;
    if (fy < 64) {
        int f0 = fy * 32;
        u16* D = whT + (size_t)b * 1024 * 3072;
#pragma unroll
        for (int p = 0; p < 4; ++p)
            tile[ty + 8 * p][tx] = S[(size_t)(f0 + ty + 8 * p) * 1024 + t0 + tx];
        __syncthreads();
#pragma unroll
        for (int p = 0; p < 4; ++p) {
            size_t o = (size_t)(t0 + ty + 8 * p) * 3072 + f0 + tx;
            D[o] = f2s(s2f(D[o]) + tile[tx][ty + 8 * p]);
        }
    } else {
        int d0 = (fy - 64) * 32;
#pragma unroll
        for (int p = 0; p < 4; ++p) {
            int d = d0 + ty + 8 * p;
            size_t ui = ((size_t)2048 + d) * 1024 + t0 + tx;
            size_t vi = (size_t)d * 4096 + (size_t)b * KLEN + t0 + tx;
            vT[vi] = f2s(s2f(vT[vi]) + S[ui]);
        }
    }
}

// ---- MFMA GEMM (m97-style): C^T(N x M) = A(M x K, bf16) @ B^T(N x K, bf16) ----
// SPLIT>1: z-th partial -> private f32 buffer: z<2 at fOut + z*pstride, z>=2 at
//          fOut2 + (z-2)*pstride2 (no atomics; consumer sums partials).
// vTout: for m0 >= 2048 (qkv V-third), write transposed to vTout[m-2048][n].
// qskip: skip blocks computing the dead Q-third x (t < 512) region of qkv.
// A2/B2/C2: piggyback r-gemm (N=256, M=1024, same K) on grid row y == gridDim.y-1.
template<int BN, int SPLIT>
__global__ __launch_bounds__(256) void gemm_bt(
    const u16* __restrict__ A,
    const u16* __restrict__ B,
    u16* __restrict__ C,
    float* __restrict__ fOut,
    int M, int K,
    const float* __restrict__ bias,
    int relu,
    int qskip,
    long pstride,
    u16* __restrict__ vTout,
    const u16* __restrict__ A2,
    const u16* __restrict__ B2,
    u16* __restrict__ C2,
    float* __restrict__ fOut2,
    long pstride2)
{
    constexpr int BM = 128, BK = 64;
    constexpr int MI = (BN == 128) ? 4 : 2;
    constexpr int NI = 4;
    int n0, m0, Mv;
    const u16* Ap; const u16* Bp; u16* Cp;
    bool isR = false;
    if (A2 && blockIdx.y == gridDim.y - 1) {
        if (blockIdx.x >= 32) return;          // r: 4 n-tiles x 8 m-tiles
        isR = true;
        n0 = (blockIdx.x & 3) * BN;
        m0 = (blockIdx.x >> 2) * BM;
        Ap = A2; Bp = B2; Cp = C2; Mv = 1024;
    } else {
        n0 = blockIdx.x * BN; m0 = blockIdx.y * BM;
        if (qskip && m0 + BM <= 1024 && (n0 & 1023) < 512) return;
        Ap = A; Bp = B; Cp = C; Mv = M;
    }
    const int Ks = K / SPLIT;
    const int kbeg = blockIdx.z * Ks;
    __shared__ __align__(16) u16 As[BM * BK];
    __shared__ __align__(16) u16 Bs[BN * BK];
    const int tid = threadIdx.x, lane = tid & 63, wv = tid >> 6;
    const int l15 = lane & 15, quad = lane >> 4;
    const int wm = (BN == 128) ? (wv >> 1) * 64 : wv * 32;
    const int wn = (BN == 128) ? (wv & 1) * 64 : 0;
    f4v acc[MI][NI] = {};
    for (int kk = kbeg; kk < kbeg + Ks; kk += BK) {
        __syncthreads();
#pragma unroll
        for (int p = 0; p < (BM * 8) / 256; ++p) {
            int c = p * 256 + tid, r = c >> 3, q = c & 7, qs = q ^ (r & 7);
            gl2lds16(&Ap[(size_t)(m0 + r) * K + kk + qs * 8], &As[c * 8]);
        }
#pragma unroll
        for (int p = 0; p < (BN * 8) / 256; ++p) {
            int c = p * 256 + tid, r = c >> 3, q = c & 7, qs = q ^ (r & 7);
            gl2lds16(&Bp[(size_t)(n0 + r) * K + kk + qs * 8], &Bs[c * 8]);
        }
        __syncthreads();
#pragma unroll
        for (int k0 = 0; k0 < BK; k0 += 32) {
            s8v af[MI], bf[NI];
#pragma unroll
            for (int mi = 0; mi < MI; ++mi) {
                int r = wm + mi * 16 + l15;
                af[mi] = *(const s8v*)&As[r * BK + ((((k0 >> 3) + quad) ^ (r & 7)) << 3)];
            }
#pragma unroll
            for (int ni = 0; ni < NI; ++ni) {
                int r = wn + ni * 16 + l15;
                bf[ni] = *(const s8v*)&Bs[r * BK + ((((k0 >> 3) + quad) ^ (r & 7)) << 3)];
            }
#pragma unroll
            for (int mi = 0; mi < MI; ++mi)
#pragma unroll
                for (int ni = 0; ni < NI; ++ni)
                    acc[mi][ni] = __builtin_amdgcn_mfma_f32_16x16x32_bf16(af[mi], bf[ni], acc[mi][ni], 0, 0, 0);
        }
    }
    if (SPLIT > 1) {
        int z = blockIdx.z;
        float* base = (z < 2) ? fOut + (long)z * pstride
                              : fOut2 + (long)(z - 2) * pstride2;
#pragma unroll
        for (int mi = 0; mi < MI; ++mi) {
            int m = m0 + wm + mi * 16 + quad * 4;
#pragma unroll
            for (int ni = 0; ni < NI; ++ni) {
                int n = n0 + wn + ni * 16 + l15;
                *(f4v*)&base[(size_t)n * Mv + m] = acc[mi][ni];   // plain 16B store, no RMW
            }
        }
    } else if (vTout && !isR && m0 >= 2048) {
        // V third of qkv: pure coalesced stores to V^T[d][n]
#pragma unroll
        for (int mi = 0; mi < MI; ++mi) {
            int m = m0 + wm + mi * 16 + quad * 4;
#pragma unroll
            for (int ni = 0; ni < NI; ++ni) {
                int n = n0 + wn + ni * 16 + l15;
#pragma unroll
                for (int r2 = 0; r2 < 4; ++r2)
                    vTout[(size_t)(m + r2 - 2048) * 4096 + n] = f2s(acc[mi][ni][r2]);
            }
        }
    } else {
#pragma unroll
        for (int mi = 0; mi < MI; ++mi) {
            int m = m0 + wm + mi * 16 + quad * 4;
            float bv[4] = {0.f, 0.f, 0.f, 0.f};
            if (bias && !isR) {
#pragma unroll
                for (int r2 = 0; r2 < 4; ++r2) bv[r2] = bias[m + r2];
            }
#pragma unroll
            for (int ni = 0; ni < NI; ++ni) {
                int n = n0 + wn + ni * 16 + l15;
                float o[4];
#pragma unroll
                for (int r2 = 0; r2 < 4; ++r2) o[r2] = acc[mi][ni][r2] + bv[r2];
                if (relu && !isR) {
#pragma unroll
                    for (int r2 = 0; r2 < 4; ++r2) o[r2] = fmaxf(o[r2], 0.f);
                }
                s4v st;
#pragma unroll
                for (int r2 = 0; r2 < 4; ++r2) st[r2] = (short)f2s(o[r2]);
                *(s4v*)&Cp[(size_t)n * Mv + m] = st;
            }
        }
    }
}

// ---- MFMA banded flash attention (v4: QT=64, direct-global K/V, LDS = S only) ----
#define QT 64
#define SROW 260   // f32 row stride: 260 % 32 == 4 -> spreads rows across banks
__global__ __launch_bounds__(256, 2) void attn_mfma(
    const u16* __restrict__ WHT,      // (BSZ, KLEN, 3*DM) bf16 (Q,K thirds valid)
    const u16* __restrict__ VT,       // (DM, BSZ*KLEN) bf16 = V^T (+uss), cols n=b*1024+t
    const u16* __restrict__ RT,       // (WIN, DM) bf16
    const float* __restrict__ rwb, const float* __restrict__ rrb,
    u16* __restrict__ avT)            // (BSZ, QLEN, DM) bf16
{
    __shared__ __align__(16) float sS[QT * SROW];   // 66560 B -> 2 blocks/CU

    const int qt = blockIdx.x, n = blockIdx.y, b = blockIdx.z;
    const int i0 = qt * QT, j0 = i0 + WIN + 1;
    const int tid = threadIdx.x, lane = tid & 63, wv = tid >> 6;
    const int l15 = lane & 15, quad = lane >> 4;
    const u16* W = WHT + (size_t)b * KLEN * (3 * DM);

    // Q fragments for 4 row-sets (A-operand rows = l15 = qi within set), biases baked in
    s8v qac[4][2], qbd[4][2];
#pragma unroll
    for (int h = 0; h < 4; ++h) {
        int qrow = MLEN + i0 + 16 * h + l15;
#pragma unroll
        for (int kc = 0; kc < 2; ++kc) {
            int col = n * DH + kc * 32 + quad * 8;
            s8v qv = *(const s8v*)&W[(size_t)qrow * (3 * DM) + col];
            s8v a, c;
#pragma unroll
            for (int e = 0; e < 8; ++e) {
                float qf = s2f((u16)qv[e]);
                a[e] = (short)f2s(qf + rwb[col + e]);
                c[e] = (short)f2s(qf + rrb[col + e]);
            }
            qac[h][kc] = a; qbd[h][kc] = c;
        }
    }

    // Phase 1: S[qi][t] = AC (QK^T); 20 k-tiles cover c in [0,320)
    for (int ci = wv; ci < 20; ci += 4) {
        int j = j0 + ci * 16 + l15; if (j > KLEN - 1) j = KLEN - 1;
        const u16* Kr = &W[(size_t)j * (3 * DM) + DM + n * DH + quad * 8];
        s8v k0 = *(const s8v*)Kr, k1 = *(const s8v*)(Kr + 32);
#pragma unroll
        for (int h = 0; h < 4; ++h) {
            f4v acc = {};
            acc = __builtin_amdgcn_mfma_f32_16x16x32_bf16(qac[h][0], k0, acc, 0, 0, 0);
            acc = __builtin_amdgcn_mfma_f32_16x16x32_bf16(qac[h][1], k1, acc, 0, 0, 0);
#pragma unroll
            for (int r2 = 0; r2 < 4; ++r2) {
                int qi = 16 * h + quad * 4 + r2;
                int t = ci * 16 + l15 - qi;
                if ((unsigned)t < 256u) sS[qi * SROW + t] = acc[r2];
            }
        }
    }
    __syncthreads();

    // Phase 2: S[qi][t'] += BD (rr_q @ R^T)
#pragma unroll
    for (int cc = 0; cc < 4; ++cc) {
        int ci = wv + cc * 4;
        const u16* Rr = &RT[(size_t)(ci * 16 + l15) * DM + n * DH + quad * 8];
        s8v r0 = *(const s8v*)Rr, r1 = *(const s8v*)(Rr + 32);
#pragma unroll
        for (int h = 0; h < 4; ++h) {
            f4v acc = {};
            acc = __builtin_amdgcn_mfma_f32_16x16x32_bf16(qbd[h][0], r0, acc, 0, 0, 0);
            acc = __builtin_amdgcn_mfma_f32_16x16x32_bf16(qbd[h][1], r1, acc, 0, 0, 0);
#pragma unroll
            for (int r2 = 0; r2 < 4; ++r2) {
                int qi = 16 * h + quad * 4 + r2;
                sS[qi * SROW + ci * 16 + l15] += acc[r2];
            }
        }
    }
    __syncthreads();

    // Phase 3: softmax; P (bf16) in-place at c' = qi + 1 + t'; zeros pad to 320
    {
        int g = tid >> 4, l = tid & 15;
#pragma unroll
        for (int h = 0; h < 4; ++h) {
            int r = g + 16 * h;
            float vals[16], mx = -1e30f;
#pragma unroll
            for (int k = 0; k < 16; ++k) {
                float s = sS[r * SROW + l + 16 * k] * 0.125f;
                vals[k] = s; mx = fmaxf(mx, s);
            }
            asm volatile("" ::: "memory");   // fence: S f32 reads before u16 P writes (aliased)
#pragma unroll
            for (int d = 1; d < 16; d <<= 1) mx = fmaxf(mx, __shfl_xor(mx, d, 16));
            float sum = 0.f;
#pragma unroll
            for (int k = 0; k < 16; ++k) { vals[k] = __expf(vals[k] - mx); sum += vals[k]; }
#pragma unroll
            for (int d = 1; d < 16; d <<= 1) sum += __shfl_xor(sum, d, 16);
            float inv = 1.f / sum;
            u16* sPr = (u16*)&sS[r * SROW];
#pragma unroll
            for (int k = 0; k < 16; ++k) sPr[r + 1 + l + 16 * k] = f2s(vals[k] * inv);
            for (int p = l; p <= r; p += 16) sPr[p] = 0;               // leading zeros [0, r]
            for (int p = r + 257 + l; p < 320; p += 16) sPr[p] = 0;    // trailing [r+257, 320)
        }
    }
    __syncthreads();

    // Phase 4: O = P @ V; V fragment loaded once, used by all 4 row-sets; 10 k-chunks
    const u16* sPu = (const u16*)sS;
    const size_t vbase = (size_t)(n * DH + wv * 16 + l15) * 4096
                       + (size_t)b * KLEN + (j0 - 1) + quad * 8;
    f4v o[4] = {};
#pragma unroll
    for (int kc = 0; kc < 10; ++kc) {
        s8v bb = *(const s8v*)&VT[vbase + kc * 32];
#pragma unroll
        for (int h = 0; h < 4; ++h) {
            s8v a = *(const s8v*)&sPu[(size_t)(16 * h + l15) * (2 * SROW) + kc * 32 + quad * 8];
            o[h] = __builtin_amdgcn_mfma_f32_16x16x32_bf16(a, bb, o[h], 0, 0, 0);
        }
    }
#pragma unroll
    for (int h = 0; h < 4; ++h)
#pragma unroll
        for (int r2 = 0; r2 < 4; ++r2) {
            int qi = quad * 4 + r2;
            avT[((size_t)b * QLEN + i0 + 16 * h + qi) * DM + n * DH + wv * 16 + l15] = f2s(o[h][r2]);
        }
}

// ---- layernorm (mid): out = LN(2 partials + bias + res_bf16) -> bf16 row-major ----
__global__ __launch_bounds__(256) void ln_f(
    const float* __restrict__ P, long pstride, int nparts,
    const float* __restrict__ bias,
    const u16* __restrict__ res, int resMode, u16* __restrict__ out)
{
    int n = blockIdx.x, tid = threadIdx.x;
    int lane = tid & 63, wv = tid >> 6;
    int f = tid * 4;
    int rrow = resMode ? (((n >> 9) * 2 + 1) * 512 + (n & 511)) : n;
    f4v pv = *(const f4v*)&P[(size_t)n * DM + f];
    for (int p = 1; p < nparts; ++p) {
        const float* Pp = P + (long)p * pstride;
        pv += *(const f4v*)&Pp[(size_t)n * DM + f];
    }
    s4v rv = *(const s4v*)&res[(size_t)rrow * DM + f];
    f4v bv = *(const f4v*)&bias[f];
    float v[4];
#pragma unroll
    for (int k = 0; k < 4; ++k) v[k] = pv[k] + bv[k] + s2f((u16)rv[k]);
    float s = v[0] + v[1] + v[2] + v[3];
    float ss = v[0] * v[0] + v[1] * v[1] + v[2] * v[2] + v[3] * v[3];
#pragma unroll
    for (int d = 1; d < 64; d <<= 1) {
        s += __shfl_xor(s, d, 64);
        ss += __shfl_xor(ss, d, 64);
    }
    __shared__ float ps[4], pss[4];
    if (lane == 0) { ps[wv] = s; pss[wv] = ss; }
    __syncthreads();
    float S = ps[0] + ps[1] + ps[2] + ps[3];
    float SS = pss[0] + pss[1] + pss[2] + pss[3];
    float m = S * (1.f / DM);
    float var = SS * (1.f / DM) - m * m;
    float inv = rsqrtf(fmaxf(var, 0.f) + 1e-5f);
    s4v st;
#pragma unroll
    for (int k = 0; k < 4; ++k) st[k] = (short)f2s((v[k] - m) * inv);
    *(s4v*)&out[(size_t)n * DM + f] = st;
}

// ---- final: out_f32[b][f][q] = LN(4 partials + bias + res_bf16), fused transpose ----
// 16 rows per block; rows staged raw in LDS (stride 1030: pass-2 reads <=2-way banks);
// 16-lane-group LN reduce; transposed coalesced f32 stores (16 lanes x 4 B segments).
#define LNR 16
#define LROW 1030
__global__ __launch_bounds__(256) void ln_out(
    const float* __restrict__ P0, const float* __restrict__ P1,
    const float* __restrict__ P2, const float* __restrict__ P3,
    const float* __restrict__ bias, const u16* __restrict__ res,
    float* __restrict__ out)
{
    __shared__ float rows[LNR * LROW];   // 65920 B
    __shared__ float sm[LNR], si[LNR];
    int n0 = blockIdx.x * LNR;
    int tid = threadIdx.x;
    int r = tid >> 4, l = tid & 15;
    int n = n0 + r;
    float s = 0.f, ss = 0.f;
    for (int k = 0; k < 16; ++k) {
        int f = (l + 16 * k) * 4;
        f4v v = *(const f4v*)&P0[(size_t)n * DM + f];
        v += *(const f4v*)&P1[(size_t)n * DM + f];
        v += *(const f4v*)&P2[(size_t)n * DM + f];
        v += *(const f4v*)&P3[(size_t)n * DM + f];
        s4v rv = *(const s4v*)&res[(size_t)n * DM + f];
        f4v bv = *(const f4v*)&bias[f];
        float* dst = &rows[r * LROW + f];
#pragma unroll
        for (int j = 0; j < 4; ++j) {
            float x = v[j] + bv[j] + s2f((u16)rv[j]);
            dst[j] = x;
            s += x; ss += x * x;
        }
    }
#pragma unroll
    for (int d = 1; d < 16; d <<= 1) {
        s += __shfl_xor(s, d, 16);
        ss += __shfl_xor(ss, d, 16);
    }
    if (l == 0) {
        float m = s * (1.f / DM);
        float var = ss * (1.f / DM) - m * m;
        sm[r] = m; si[r] = rsqrtf(fmaxf(var, 0.f) + 1e-5f);
    }
    __syncthreads();
    // transposed write: out[b][f][q0+qi]
    int b = n0 >> 9, q0 = n0 & 511;
    int qi = tid & 15, g = tid >> 4;
    float m = sm[qi], inv = si[qi];
    float* O = out + (size_t)b * DM * QLEN + q0 + qi;
    for (int k = 0; k < 64; ++k) {
        int f = g + 16 * k;
        O[(size_t)f * QLEN] = (rows[qi * LROW + f] - m) * inv;
    }
}

extern "C" void kernel_launch(void* const* d_in, const int* in_sizes, int n_in,
                              void* d_out, int out_size, void* d_ws, size_t ws_size,
                              hipStream_t stream) {
    const float* z1ss  = (const float*)d_in[0];
    const float* uss   = (const float*)d_in[1];
    const float* z0    = (const float*)d_in[2];
    const float* pos   = (const float*)d_in[3];
    const float* qkv_w = (const float*)d_in[4];
    const float* r_w   = (const float*)d_in[5];
    const float* rwb   = (const float*)d_in[6];
    const float* rrb   = (const float*)d_in[7];
    const float* o_w   = (const float*)d_in[8];
    const float* o_b   = (const float*)d_in[9];
    const float* ff1_w = (const float*)d_in[10];
    const float* ff1_b = (const float*)d_in[11];
    const float* ff2_w = (const float*)d_in[12];
    const float* ff2_b = (const float*)d_in[13];

    u16* ws = (u16*)d_ws;
    u16* wQ   = ws;             // [0,6) MB
    u16* wR   = ws + 3145728;   // [6,8)
    u16* wO   = ws + 4194304;   // [8,10)
    u16* wF1  = ws + 5242880;   // [10,18)
    u16* wF2  = ws + 9437184;   // [18,26)
    u16* catT = ws + 13631488;  // [26,34)  (4,1024,1024)
    u16* whT  = ws + 17825792;  // [34,58)  (4,1024,3072); later aliased as hT
    u16* posT = ws + 30408704;  // [58,58.5)
    u16* rT   = ws + 30670848;  // [58.5,59)
    u16* avT  = ws + 30932992;  // [59,63)  (2048,1024)
    u16* xT   = ws + 33030144;  // [63,67)  (2048,1024)
    float* pref = (float*)(ws + 35127296);  // [67,75) f32 (split partial 0)
    u16* hT   = whT;

    // vT (1024 x 4096 bf16, = 8 MB) aliases pref: live only between qkv gemm and attn.
    u16* vT = (u16*)pref;

    // split partials: p1 at ws+0 (wQ/wR, dead once o-proj/ff2 run);
    // ff2 extras: p2 at byte 8 MB (wO+wF1, dead after ff1), p3 at catT (dead after ln1).
    float* part1 = (float*)d_ws;
    float* part2 = (float*)(ws + 4194304);
    float* part3 = (float*)catT;
    long pstr  = part1 - pref;     // z=0 -> pref, z=1 -> part1
    long pstr2 = part3 - part2;    // z=2 -> part2, z=3 -> part3

    dim3 tblk(32, 8);

    // fused weight-convert + input transposes
    prep<<<CONV_BLKS + Z0_BLKS + Z1_BLKS + POS_BLKS, 256, 0, stream>>>(
        qkv_w, r_w, o_w, ff1_w, ff2_w, wQ, wR, wO, wF1, wF2,
        z0, z1ss, pos, catT, posT);

    // qkv + piggybacked r-gemm (grid row y=24): whT Q/K thirds; V third -> vT; rT
    gemm_bt<64, 1><<<dim3(64, 25, 1), 256, 0, stream>>>(
        wQ, catT, whT, nullptr, 3 * DM, DM, nullptr, 0, 1, 0, vT,
        wR, posT, rT, nullptr, 0);

    // uss: Q/K thirds transpose-add into whT; V third straight-add into vT
    uss_add<<<dim3(32, 96, BSZ), tblk, 0, stream>>>(uss, whT, vT);

    // MFMA banded attention -> avT  (QT=64: 512 blocks, 2/CU)
    attn_mfma<<<dim3(QLEN / QT, NH, BSZ), 256, 0, stream>>>(whT, vT, rT, rwb, rrb, avT);

    // o-proj split-2, private partials (overwrites pref/vT: attn already consumed vT)
    gemm_bt<64, 2><<<dim3(32, 8, 2), 256, 0, stream>>>(
        wO, avT, nullptr, pref, DM, DM, nullptr, 0, 0, pstr, nullptr,
        nullptr, nullptr, nullptr, nullptr, 0);

    ln_f<<<2048, 256, 0, stream>>>(pref, pstr, 2, o_b, catT, 1, xT);

    // ff1
    gemm_bt<64, 1><<<dim3(32, 32, 1), 256, 0, stream>>>(
        wF1, xT, hT, nullptr, DI, DM, ff1_b, 1, 0, 0, nullptr,
        nullptr, nullptr, nullptr, nullptr, 0);

    // ff2 split-4, private partials (pref, part1, part2, part3)
    gemm_bt<64, 4><<<dim3(32, 8, 4), 256, 0, stream>>>(
        wF2, hT, nullptr, pref, DM, DI, nullptr, 0, 0, pstr, nullptr,
        nullptr, nullptr, nullptr, part2, pstr2);

    // final LN + transposed f32 output (replaces ln_f + trans_b2f)
    ln_out<<<2048 / LNR, 256, 0, stream>>>(
        pref, part1, part2, part3, ff2_b, xT, (float*)d_out);
}

// Round 9
// 304.175 us; speedup vs baseline: 1.1730x; 1.0471x over previous
//
#include <hip/hip_runtime.h>
#include <hip/hip_bf16.h>

typedef unsigned short u16;
typedef __attribute__((ext_vector_type(8))) short s8v;
typedef __attribute__((ext_vector_type(4))) short s4v;
typedef __attribute__((ext_vector_type(4))) float f4v;

__device__ __forceinline__ float s2f(u16 s) {
    unsigned int u = ((unsigned int)s) << 16;
    return __builtin_bit_cast(float, u);
}
__device__ __forceinline__ u16 f2s(float f) {
    __hip_bfloat16 h = __float2bfloat16(f);
    return __builtin_bit_cast(u16, h);
}

// async global->LDS DMA, 16 B per lane; LDS dst must be lane-linear
__device__ __forceinline__ void gl2lds16(const u16* g, u16* l) {
    __builtin_amdgcn_global_load_lds((const __attribute__((address_space(1))) void*)g,
                                     (__attribute__((address_space(3))) void*)l, 16, 0, 0);
}

#define BSZ 4
#define DM 1024
#define QLEN 512
#define MLEN 512
#define KLEN 1024
#define DI 4096
#define NH 16
#define DH 64
#define WIN 256   // valid keys: j = i+257 .. i+512 (exactly 256 per query, never clipped)

// ---- fused prep: weight f32->bf16 conversion + z0/z1ss/pos transposes (1 launch) ----
#define CONV_BLKS 13312
#define Z0_BLKS 2048
#define Z1_BLKS 2048
#define POS_BLKS 256
__global__ __launch_bounds__(256) void prep(
    const float* __restrict__ qkv_w, const float* __restrict__ r_w,
    const float* __restrict__ o_w, const float* __restrict__ ff1_w,
    const float* __restrict__ ff2_w,
    u16* __restrict__ wQ, u16* __restrict__ wR, u16* __restrict__ wO,
    u16* __restrict__ wF1, u16* __restrict__ wF2,
    const float* __restrict__ z0, const float* __restrict__ z1ss,
    const float* __restrict__ pos,
    u16* __restrict__ catT, u16* __restrict__ posT)
{
    int bx = blockIdx.x, tid = threadIdx.x;
    if (bx < CONV_BLKS) {
        const int e0 = 786432, e1 = e0 + 262144, e2 = e1 + 262144, e3 = e2 + 1048576;
        int i = bx * 256 + tid;
        const float* s; u16* d; int off;
        if (i < e0)      { s = qkv_w; d = wQ;  off = i; }
        else if (i < e1) { s = r_w;   d = wR;  off = i - e0; }
        else if (i < e2) { s = o_w;   d = wO;  off = i - e1; }
        else if (i < e3) { s = ff1_w; d = wF1; off = i - e2; }
        else             { s = ff2_w; d = wF2; off = i - e3; }
        f4v v = *(const f4v*)&s[(size_t)off * 4];
        s4v o;
#pragma unroll
        for (int k = 0; k < 4; ++k) o[k] = (short)f2s(v[k]);
        *(s4v*)&d[(size_t)off * 4] = o;
        return;
    }
    __shared__ float tile[32][33];
    int tx = tid & 31, ty = tid >> 5;   // (32, 8)
    const float* src; u16* dst; long sS, sD; int ldS, ldD, colOff, rowOff, t0, f0, b;
    if (bx < CONV_BLKS + Z0_BLKS) {
        int idx = bx - CONV_BLKS;
        t0 = (idx & 15) * 32; f0 = ((idx >> 4) & 31) * 32; b = idx >> 9;
        src = z0;   sS = (long)DM * MLEN; ldS = MLEN; colOff = 0;
        dst = catT; sD = (long)KLEN * DM; ldD = DM;  rowOff = 0;
    } else if (bx < CONV_BLKS + Z0_BLKS + Z1_BLKS) {
        int idx = bx - CONV_BLKS - Z0_BLKS;
        t0 = (idx & 15) * 32; f0 = ((idx >> 4) & 31) * 32; b = idx >> 9;
        src = z1ss; sS = (long)DM * QLEN; ldS = QLEN; colOff = 0;
        dst = catT; sD = (long)KLEN * DM; ldD = DM;  rowOff = MLEN;
    } else {
        int idx = bx - CONV_BLKS - Z0_BLKS - Z1_BLKS;
        t0 = (idx & 7) * 32; f0 = (idx >> 3) * 32; b = 0;
        src = pos;  sS = 0; ldS = KLEN; colOff = KLEN - WIN;
        dst = posT; sD = 0; ldD = DM;   rowOff = 0;
    }
#pragma unroll
    for (int p = 0; p < 4; ++p)
        tile[ty + 8 * p][tx] = src[(size_t)b * sS + (size_t)(f0 + ty + 8 * p) * ldS + colOff + t0 + tx];
    __syncthreads();
#pragma unroll
    for (int p = 0; p < 4; ++p)
        dst[(size_t)b * sD + (size_t)(rowOff + t0 + ty + 8 * p) * ldD + f0 + tx] = f2s(tile[tx][ty + 8 * p]);
}

// ---- MFMA GEMM (m97-style): C^T(N x M) = A(M x K, bf16) @ B^T(N x K, bf16) ----
// SPLIT>1: z-th partial -> private f32 buffer: z<2 at fOut + z*pstride, z>=2 at
//          fOut2 + (z-2)*pstride2 (no atomics; consumer sums partials).
// uss: f32 [b][3072][1024], n = b*1024 + t; added in-epilogue (64-B aligned segment
//      reads: 16 lanes x consecutive t). Single f32 rounding (better than RMW pass).
// vTout: for m0 >= 2048 (qkv V-third), write transposed to vTout[m-2048][n] (+uss).
// qskip: Q-third x (t<512) output is dead; those blocks early-exit, EXCEPT 32 of the
//        y==0 holes which are remapped as the piggybacked r-gemm (A2/B2/C2, N=256).
template<int BN, int SPLIT>
__global__ __launch_bounds__(256) void gemm_bt(
    const u16* __restrict__ A,
    const u16* __restrict__ B,
    u16* __restrict__ C,
    float* __restrict__ fOut,
    int M, int K,
    const float* __restrict__ bias,
    int relu,
    int qskip,
    long pstride,
    const float* __restrict__ uss,
    u16* __restrict__ vTout,
    const u16* __restrict__ A2,
    const u16* __restrict__ B2,
    u16* __restrict__ C2,
    float* __restrict__ fOut2,
    long pstride2)
{
    constexpr int BM = 128, BK = 64;
    constexpr int MI = (BN == 128) ? 4 : 2;
    constexpr int NI = 4;
    int n0 = blockIdx.x * BN, m0 = blockIdx.y * BM, Mv = M;
    const u16* Ap = A; const u16* Bp = B; u16* Cp = C;
    bool isR = false;
    if (qskip && m0 + BM <= 1024 && (n0 & 1023) < 512) {
        // dead Q-third x (t<512) block; y==0 holes host the r-gemm (32 blocks)
        if (A2 && blockIdx.y == 0) {
            int rid = (blockIdx.x & 7) | ((blockIdx.x >> 4) << 3);   // 0..31, unique
            isR = true;
            n0 = (rid & 3) * BN;
            m0 = (rid >> 2) * BM;
            Ap = A2; Bp = B2; Cp = C2; Mv = 1024;
        } else return;
    }
    const int Ks = K / SPLIT;
    const int kbeg = blockIdx.z * Ks;
    __shared__ __align__(16) u16 As[BM * BK];
    __shared__ __align__(16) u16 Bs[BN * BK];
    const int tid = threadIdx.x, lane = tid & 63, wv = tid >> 6;
    const int l15 = lane & 15, quad = lane >> 4;
    const int wm = (BN == 128) ? (wv >> 1) * 64 : wv * 32;
    const int wn = (BN == 128) ? (wv & 1) * 64 : 0;
    f4v acc[MI][NI] = {};
    for (int kk = kbeg; kk < kbeg + Ks; kk += BK) {
        __syncthreads();
#pragma unroll
        for (int p = 0; p < (BM * 8) / 256; ++p) {
            int c = p * 256 + tid, r = c >> 3, q = c & 7, qs = q ^ (r & 7);
            gl2lds16(&Ap[(size_t)(m0 + r) * K + kk + qs * 8], &As[c * 8]);
        }
#pragma unroll
        for (int p = 0; p < (BN * 8) / 256; ++p) {
            int c = p * 256 + tid, r = c >> 3, q = c & 7, qs = q ^ (r & 7);
            gl2lds16(&Bp[(size_t)(n0 + r) * K + kk + qs * 8], &Bs[c * 8]);
        }
        __syncthreads();
#pragma unroll
        for (int k0 = 0; k0 < BK; k0 += 32) {
            s8v af[MI], bf[NI];
#pragma unroll
            for (int mi = 0; mi < MI; ++mi) {
                int r = wm + mi * 16 + l15;
                af[mi] = *(const s8v*)&As[r * BK + ((((k0 >> 3) + quad) ^ (r & 7)) << 3)];
            }
#pragma unroll
            for (int ni = 0; ni < NI; ++ni) {
                int r = wn + ni * 16 + l15;
                bf[ni] = *(const s8v*)&Bs[r * BK + ((((k0 >> 3) + quad) ^ (r & 7)) << 3)];
            }
#pragma unroll
            for (int mi = 0; mi < MI; ++mi)
#pragma unroll
                for (int ni = 0; ni < NI; ++ni)
                    acc[mi][ni] = __builtin_amdgcn_mfma_f32_16x16x32_bf16(af[mi], bf[ni], acc[mi][ni], 0, 0, 0);
        }
    }
    if (SPLIT > 1) {
        int z = blockIdx.z;
        float* base = (z < 2) ? fOut + (long)z * pstride
                              : fOut2 + (long)(z - 2) * pstride2;
#pragma unroll
        for (int mi = 0; mi < MI; ++mi) {
            int m = m0 + wm + mi * 16 + quad * 4;
#pragma unroll
            for (int ni = 0; ni < NI; ++ni) {
                int n = n0 + wn + ni * 16 + l15;
                *(f4v*)&base[(size_t)n * Mv + m] = acc[mi][ni];   // plain 16B store, no RMW
            }
        }
    } else if (vTout && !isR && m0 >= 2048) {
        // V third of qkv: vT[d][n] = prod + uss (uss feature-major = coalesced in t)
#pragma unroll
        for (int mi = 0; mi < MI; ++mi) {
            int m = m0 + wm + mi * 16 + quad * 4;
#pragma unroll
            for (int ni = 0; ni < NI; ++ni) {
                int n = n0 + wn + ni * 16 + l15;
                int b = n >> 10, t = n & 1023;
#pragma unroll
                for (int r2 = 0; r2 < 4; ++r2) {
                    float u = uss[((size_t)b * 3072 + m + r2) * 1024 + t];
                    vTout[(size_t)(m + r2 - 2048) * 4096 + n] = f2s(acc[mi][ni][r2] + u);
                }
            }
        }
    } else {
#pragma unroll
        for (int mi = 0; mi < MI; ++mi) {
            int m = m0 + wm + mi * 16 + quad * 4;
            float bv[4] = {0.f, 0.f, 0.f, 0.f};
            if (bias && !isR) {
#pragma unroll
                for (int r2 = 0; r2 < 4; ++r2) bv[r2] = bias[m + r2];
            }
#pragma unroll
            for (int ni = 0; ni < NI; ++ni) {
                int n = n0 + wn + ni * 16 + l15;
                float o[4];
#pragma unroll
                for (int r2 = 0; r2 < 4; ++r2) o[r2] = acc[mi][ni][r2] + bv[r2];
                if (uss && !isR) {
                    int b = n >> 10, t = n & 1023;
#pragma unroll
                    for (int r2 = 0; r2 < 4; ++r2)
                        o[r2] += uss[((size_t)b * 3072 + m + r2) * 1024 + t];
                }
                if (relu && !isR) {
#pragma unroll
                    for (int r2 = 0; r2 < 4; ++r2) o[r2] = fmaxf(o[r2], 0.f);
                }
                s4v st;
#pragma unroll
                for (int r2 = 0; r2 < 4; ++r2) st[r2] = (short)f2s(o[r2]);
                *(s4v*)&Cp[(size_t)n * Mv + m] = st;
            }
        }
    }
}

// ---- MFMA banded flash attention (v4: QT=64, direct-global K/V, LDS = S only) ----
#define QT 64
#define SROW 260   // f32 row stride: 260 % 32 == 4 -> spreads rows across banks
__global__ __launch_bounds__(256, 2) void attn_mfma(
    const u16* __restrict__ WHT,      // (BSZ, KLEN, 3*DM) bf16 (Q,K thirds valid, uss baked)
    const u16* __restrict__ VT,       // (DM, BSZ*KLEN) bf16 = V^T (+uss), cols n=b*1024+t
    const u16* __restrict__ RT,       // (WIN, DM) bf16
    const float* __restrict__ rwb, const float* __restrict__ rrb,
    u16* __restrict__ avT)            // (BSZ, QLEN, DM) bf16
{
    __shared__ __align__(16) float sS[QT * SROW];   // 66560 B -> 2 blocks/CU

    const int qt = blockIdx.x, n = blockIdx.y, b = blockIdx.z;
    const int i0 = qt * QT, j0 = i0 + WIN + 1;
    const int tid = threadIdx.x, lane = tid & 63, wv = tid >> 6;
    const int l15 = lane & 15, quad = lane >> 4;
    const u16* W = WHT + (size_t)b * KLEN * (3 * DM);

    // Q fragments for 4 row-sets (A-operand rows = l15 = qi within set), biases baked in
    s8v qac[4][2], qbd[4][2];
#pragma unroll
    for (int h = 0; h < 4; ++h) {
        int qrow = MLEN + i0 + 16 * h + l15;
#pragma unroll
        for (int kc = 0; kc < 2; ++kc) {
            int col = n * DH + kc * 32 + quad * 8;
            s8v qv = *(const s8v*)&W[(size_t)qrow * (3 * DM) + col];
            s8v a, c;
#pragma unroll
            for (int e = 0; e < 8; ++e) {
                float qf = s2f((u16)qv[e]);
                a[e] = (short)f2s(qf + rwb[col + e]);
                c[e] = (short)f2s(qf + rrb[col + e]);
            }
            qac[h][kc] = a; qbd[h][kc] = c;
        }
    }

    // Phase 1: S[qi][t] = AC (QK^T); 20 k-tiles cover c in [0,320)
    for (int ci = wv; ci < 20; ci += 4) {
        int j = j0 + ci * 16 + l15; if (j > KLEN - 1) j = KLEN - 1;
        const u16* Kr = &W[(size_t)j * (3 * DM) + DM + n * DH + quad * 8];
        s8v k0 = *(const s8v*)Kr, k1 = *(const s8v*)(Kr + 32);
#pragma unroll
        for (int h = 0; h < 4; ++h) {
            f4v acc = {};
            acc = __builtin_amdgcn_mfma_f32_16x16x32_bf16(qac[h][0], k0, acc, 0, 0, 0);
            acc = __builtin_amdgcn_mfma_f32_16x16x32_bf16(qac[h][1], k1, acc, 0, 0, 0);
#pragma unroll
            for (int r2 = 0; r2 < 4; ++r2) {
                int qi = 16 * h + quad * 4 + r2;
                int t = ci * 16 + l15 - qi;
                if ((unsigned)t < 256u) sS[qi * SROW + t] = acc[r2];
            }
        }
    }
    __syncthreads();

    // Phase 2: S[qi][t'] += BD (rr_q @ R^T)
#pragma unroll
    for (int cc = 0; cc < 4; ++cc) {
        int ci = wv + cc * 4;
        const u16* Rr = &RT[(size_t)(ci * 16 + l15) * DM + n * DH + quad * 8];
        s8v r0 = *(const s8v*)Rr, r1 = *(const s8v*)(Rr + 32);
#pragma unroll
        for (int h = 0; h < 4; ++h) {
            f4v acc = {};
            acc = __builtin_amdgcn_mfma_f32_16x16x32_bf16(qbd[h][0], r0, acc, 0, 0, 0);
            acc = __builtin_amdgcn_mfma_f32_16x16x32_bf16(qbd[h][1], r1, acc, 0, 0, 0);
#pragma unroll
            for (int r2 = 0; r2 < 4; ++r2) {
                int qi = 16 * h + quad * 4 + r2;
                sS[qi * SROW + ci * 16 + l15] += acc[r2];
            }
        }
    }
    __syncthreads();

    // Phase 3: softmax; P (bf16) in-place at c' = qi + 1 + t'; zeros pad to 320
    {
        int g = tid >> 4, l = tid & 15;
#pragma unroll
        for (int h = 0; h < 4; ++h) {
            int r = g + 16 * h;
            float vals[16], mx = -1e30f;
#pragma unroll
            for (int k = 0; k < 16; ++k) {
                float s = sS[r * SROW + l + 16 * k] * 0.125f;
                vals[k] = s; mx = fmaxf(mx, s);
            }
            asm volatile("" ::: "memory");   // fence: S f32 reads before u16 P writes (aliased)
#pragma unroll
            for (int d = 1; d < 16; d <<= 1) mx = fmaxf(mx, __shfl_xor(mx, d, 16));
            float sum = 0.f;
#pragma unroll
            for (int k = 0; k < 16; ++k) { vals[k] = __expf(vals[k] - mx); sum += vals[k]; }
#pragma unroll
            for (int d = 1; d < 16; d <<= 1) sum += __shfl_xor(sum, d, 16);
            float inv = 1.f / sum;
            u16* sPr = (u16*)&sS[r * SROW];
#pragma unroll
            for (int k = 0; k < 16; ++k) sPr[r + 1 + l + 16 * k] = f2s(vals[k] * inv);
            for (int p = l; p <= r; p += 16) sPr[p] = 0;               // leading zeros [0, r]
            for (int p = r + 257 + l; p < 320; p += 16) sPr[p] = 0;    // trailing [r+257, 320)
        }
    }
    __syncthreads();

    // Phase 4: O = P @ V; V fragment loaded once, used by all 4 row-sets; 10 k-chunks
    const u16* sPu = (const u16*)sS;
    const size_t vbase = (size_t)(n * DH + wv * 16 + l15) * 4096
                       + (size_t)b * KLEN + (j0 - 1) + quad * 8;
    f4v o[4] = {};
#pragma unroll
    for (int kc = 0; kc < 10; ++kc) {
        s8v bb = *(const s8v*)&VT[vbase + kc * 32];
#pragma unroll
        for (int h = 0; h < 4; ++h) {
            s8v a = *(const s8v*)&sPu[(size_t)(16 * h + l15) * (2 * SROW) + kc * 32 + quad * 8];
            o[h] = __builtin_amdgcn_mfma_f32_16x16x32_bf16(a, bb, o[h], 0, 0, 0);
        }
    }
#pragma unroll
    for (int h = 0; h < 4; ++h)
#pragma unroll
        for (int r2 = 0; r2 < 4; ++r2) {
            int qi = quad * 4 + r2;
            avT[((size_t)b * QLEN + i0 + 16 * h + qi) * DM + n * DH + wv * 16 + l15] = f2s(o[h][r2]);
        }
}

// ---- layernorm (mid): out = LN(2 partials + bias + res_bf16) -> bf16 row-major ----
__global__ __launch_bounds__(256) void ln_f(
    const float* __restrict__ P, long pstride, int nparts,
    const float* __restrict__ bias,
    const u16* __restrict__ res, int resMode, u16* __restrict__ out)
{
    int n = blockIdx.x, tid = threadIdx.x;
    int lane = tid & 63, wv = tid >> 6;
    int f = tid * 4;
    int rrow = resMode ? (((n >> 9) * 2 + 1) * 512 + (n & 511)) : n;
    f4v pv = *(const f4v*)&P[(size_t)n * DM + f];
    for (int p = 1; p < nparts; ++p) {
        const float* Pp = P + (long)p * pstride;
        pv += *(const f4v*)&Pp[(size_t)n * DM + f];
    }
    s4v rv = *(const s4v*)&res[(size_t)rrow * DM + f];
    f4v bv = *(const f4v*)&bias[f];
    float v[4];
#pragma unroll
    for (int k = 0; k < 4; ++k) v[k] = pv[k] + bv[k] + s2f((u16)rv[k]);
    float s = v[0] + v[1] + v[2] + v[3];
    float ss = v[0] * v[0] + v[1] * v[1] + v[2] * v[2] + v[3] * v[3];
#pragma unroll
    for (int d = 1; d < 64; d <<= 1) {
        s += __shfl_xor(s, d, 64);
        ss += __shfl_xor(ss, d, 64);
    }
    __shared__ float ps[4], pss[4];
    if (lane == 0) { ps[wv] = s; pss[wv] = ss; }
    __syncthreads();
    float S = ps[0] + ps[1] + ps[2] + ps[3];
    float SS = pss[0] + pss[1] + pss[2] + pss[3];
    float m = S * (1.f / DM);
    float var = SS * (1.f / DM) - m * m;
    float inv = rsqrtf(fmaxf(var, 0.f) + 1e-5f);
    s4v st;
#pragma unroll
    for (int k = 0; k < 4; ++k) st[k] = (short)f2s((v[k] - m) * inv);
    *(s4v*)&out[(size_t)n * DM + f] = st;
}

// ---- final: out_f32[b][f][q] = LN(4 partials + bias + res_bf16), fused transpose ----
#define LNR 16
#define LROW 1030
__global__ __launch_bounds__(256) void ln_out(
    const float* __restrict__ P0, const float* __restrict__ P1,
    const float* __restrict__ P2, const float* __restrict__ P3,
    const float* __restrict__ bias, const u16* __restrict__ res,
    float* __restrict__ out)
{
    __shared__ float rows[LNR * LROW];   // 65920 B
    __shared__ float sm[LNR], si[LNR];
    int n0 = blockIdx.x * LNR;
    int tid = threadIdx.x;
    int r = tid >> 4, l = tid & 15;
    int n = n0 + r;
    float s = 0.f, ss = 0.f;
    for (int k = 0; k < 16; ++k) {
        int f = (l + 16 * k) * 4;
        f4v v = *(const f4v*)&P0[(size_t)n * DM + f];
        v += *(const f4v*)&P1[(size_t)n * DM + f];
        v += *(const f4v*)&P2[(size_t)n * DM + f];
        v += *(const f4v*)&P3[(size_t)n * DM + f];
        s4v rv = *(const s4v*)&res[(size_t)n * DM + f];
        f4v bv = *(const f4v*)&bias[f];
        float* dst = &rows[r * LROW + f];
#pragma unroll
        for (int j = 0; j < 4; ++j) {
            float x = v[j] + bv[j] + s2f((u16)rv[j]);
            dst[j] = x;
            s += x; ss += x * x;
        }
    }
#pragma unroll
    for (int d = 1; d < 16; d <<= 1) {
        s += __shfl_xor(s, d, 16);
        ss += __shfl_xor(ss, d, 16);
    }
    if (l == 0) {
        float m = s * (1.f / DM);
        float var = ss * (1.f / DM) - m * m;
        sm[r] = m; si[r] = rsqrtf(fmaxf(var, 0.f) + 1e-5f);
    }
    __syncthreads();
    // transposed write: out[b][f][q0+qi]
    int b = n0 >> 9, q0 = n0 & 511;
    int qi = tid & 15, g = tid >> 4;
    float m = sm[qi], inv = si[qi];
    float* O = out + (size_t)b * DM * QLEN + q0 + qi;
    for (int k = 0; k < 64; ++k) {
        int f = g + 16 * k;
        O[(size_t)f * QLEN] = (rows[qi * LROW + f] - m) * inv;
    }
}

extern "C" void kernel_launch(void* const* d_in, const int* in_sizes, int n_in,
                              void* d_out, int out_size, void* d_ws, size_t ws_size,
                              hipStream_t stream) {
    const float* z1ss  = (const float*)d_in[0];
    const float* uss   = (const float*)d_in[1];
    const float* z0    = (const float*)d_in[2];
    const float* pos   = (const float*)d_in[3];
    const float* qkv_w = (const float*)d_in[4];
    const float* r_w   = (const float*)d_in[5];
    const float* rwb   = (const float*)d_in[6];
    const float* rrb   = (const float*)d_in[7];
    const float* o_w   = (const float*)d_in[8];
    const float* o_b   = (const float*)d_in[9];
    const float* ff1_w = (const float*)d_in[10];
    const float* ff1_b = (const float*)d_in[11];
    const float* ff2_w = (const float*)d_in[12];
    const float* ff2_b = (const float*)d_in[13];

    u16* ws = (u16*)d_ws;
    u16* wQ   = ws;             // [0,6) MB
    u16* wR   = ws + 3145728;   // [6,8)
    u16* wO   = ws + 4194304;   // [8,10)
    u16* wF1  = ws + 5242880;   // [10,18)
    u16* wF2  = ws + 9437184;   // [18,26)
    u16* catT = ws + 13631488;  // [26,34)  (4,1024,1024)
    u16* whT  = ws + 17825792;  // [34,58)  (4,1024,3072); later aliased as hT
    u16* posT = ws + 30408704;  // [58,58.5)
    u16* rT   = ws + 30670848;  // [58.5,59)
    u16* avT  = ws + 30932992;  // [59,63)  (2048,1024)
    u16* xT   = ws + 33030144;  // [63,67)  (2048,1024)
    float* pref = (float*)(ws + 35127296);  // [67,75) f32 (split partial 0)
    u16* hT   = whT;

    // vT (1024 x 4096 bf16, = 8 MB) aliases pref: live only between qkv gemm and attn.
    u16* vT = (u16*)pref;

    // split partials: p1 at ws+0 (wQ/wR, dead once o-proj/ff2 run);
    // ff2 extras: p2 at byte 8 MB (wO+wF1, dead after ff1), p3 at catT (dead after ln1).
    float* part1 = (float*)d_ws;
    float* part2 = (float*)(ws + 4194304);
    float* part3 = (float*)catT;
    long pstr  = part1 - pref;     // z=0 -> pref, z=1 -> part1
    long pstr2 = part3 - part2;    // z=2 -> part2, z=3 -> part3

    // fused weight-convert + input transposes
    prep<<<CONV_BLKS + Z0_BLKS + Z1_BLKS + POS_BLKS, 256, 0, stream>>>(
        qkv_w, r_w, o_w, ff1_w, ff2_w, wQ, wR, wO, wF1, wF2,
        z0, z1ss, pos, catT, posT);

    // qkv (+uss in-epilogue) + r-gemm in the qskip holes: whT Q/K thirds (+uss);
    // V third -> vT (+uss); rT. Grid exactly 1536 = full single-wave residency.
    gemm_bt<64, 1><<<dim3(64, 24, 1), 256, 0, stream>>>(
        wQ, catT, whT, nullptr, 3 * DM, DM, nullptr, 0, 1, 0, uss, vT,
        wR, posT, rT, nullptr, 0);

    // MFMA banded attention -> avT  (QT=64: 512 blocks, 2/CU)
    attn_mfma<<<dim3(QLEN / QT, NH, BSZ), 256, 0, stream>>>(whT, vT, rT, rwb, rrb, avT);

    // o-proj split-2, private partials (overwrites pref/vT: attn already consumed vT)
    gemm_bt<64, 2><<<dim3(32, 8, 2), 256, 0, stream>>>(
        wO, avT, nullptr, pref, DM, DM, nullptr, 0, 0, pstr, nullptr, nullptr,
        nullptr, nullptr, nullptr, nullptr, 0);

    ln_f<<<2048, 256, 0, stream>>>(pref, pstr, 2, o_b, catT, 1, xT);

    // ff1
    gemm_bt<64, 1><<<dim3(32, 32, 1), 256, 0, stream>>>(
        wF1, xT, hT, nullptr, DI, DM, ff1_b, 1, 0, 0, nullptr, nullptr,
        nullptr, nullptr, nullptr, nullptr, 0);

    // ff2 split-4, private partials (pref, part1, part2, part3)
    gemm_bt<64, 4><<<dim3(32, 8, 4), 256, 0, stream>>>(
        wF2, hT, nullptr, pref, DM, DI, nullptr, 0, 0, pstr, nullptr, nullptr,
        nullptr, nullptr, nullptr, part2, pstr2);

    // final LN + transposed f32 output
    ln_out<<<2048 / LNR, 256, 0, stream>>>(
        pref, part1, part2, part3, ff2_b, xT, (float*)d_out);
}